// Round 1
// 2596.241 us; speedup vs baseline: 1.0053x; 1.0053x over previous
//
#include <hip/hip_runtime.h>

#define N_NODES   100000
#define D_IN      512
#define NUM_CODES 2048
#define D_OUT     256
#define NCAND     16
#define RESCORE_MARGIN 0.05f

typedef float f32x4  __attribute__((ext_vector_type(4)));
typedef short bf16x8 __attribute__((ext_vector_type(8)));

__device__ __forceinline__ bool better(float s, int i, float S, int I) {
  return (s < S) || (s == S && i < I);
}

__device__ __forceinline__ unsigned short f2bf(float f) {
  unsigned int u = __float_as_uint(f);
  u = (u + 0x7fffu + ((u >> 16) & 1u)) >> 16;  // RNE
  return (unsigned short)u;
}

// async global->LDS, 16B per lane; lds ptr must be the wave-uniform base
// (HW writes lane i at base + i*16).
typedef const __attribute__((address_space(1))) unsigned int* gas_ptr;
typedef __attribute__((address_space(3))) unsigned int* las_ptr;
__device__ __forceinline__ void gload16(const void* g, void* l) {
  __builtin_amdgcn_global_load_lds((gas_ptr)g, (las_ptr)l, 16, 0, 0);
}

// ---------------------------------------------------------------------------
// numpy pairwise sum-of-squares over a 512-float row (np-exact; see r3).
// ---------------------------------------------------------------------------
__device__ __forceinline__ float np_pairwise_sq512(const float* __restrict__ a) {
  float tot[4];
#pragma unroll
  for (int b = 0; b < 4; b++) {
    const float* p = a + (b << 7);
    float r[8];
    {
      float4 q0 = *(const float4*)(p);
      float4 q1 = *(const float4*)(p + 4);
      r[0] = __fmul_rn(q0.x, q0.x); r[1] = __fmul_rn(q0.y, q0.y);
      r[2] = __fmul_rn(q0.z, q0.z); r[3] = __fmul_rn(q0.w, q0.w);
      r[4] = __fmul_rn(q1.x, q1.x); r[5] = __fmul_rn(q1.y, q1.y);
      r[6] = __fmul_rn(q1.z, q1.z); r[7] = __fmul_rn(q1.w, q1.w);
    }
    for (int i = 8; i < 128; i += 8) {
      float4 u0 = *(const float4*)(p + i);
      float4 u1 = *(const float4*)(p + i + 4);
      r[0] = __fadd_rn(r[0], __fmul_rn(u0.x, u0.x));
      r[1] = __fadd_rn(r[1], __fmul_rn(u0.y, u0.y));
      r[2] = __fadd_rn(r[2], __fmul_rn(u0.z, u0.z));
      r[3] = __fadd_rn(r[3], __fmul_rn(u0.w, u0.w));
      r[4] = __fadd_rn(r[4], __fmul_rn(u1.x, u1.x));
      r[5] = __fadd_rn(r[5], __fmul_rn(u1.y, u1.y));
      r[6] = __fadd_rn(r[6], __fmul_rn(u1.z, u1.z));
      r[7] = __fadd_rn(r[7], __fmul_rn(u1.w, u1.w));
    }
    float t01 = __fadd_rn(r[0], r[1]);
    float t23 = __fadd_rn(r[2], r[3]);
    float t45 = __fadd_rn(r[4], r[5]);
    float t67 = __fadd_rn(r[6], r[7]);
    tot[b] = __fadd_rn(__fadd_rn(t01, t23), __fadd_rn(t45, t67));
  }
  return __fadd_rn(__fadd_rn(tot[0], tot[1]), __fadd_rn(tot[2], tot[3]));
}

__global__ __launch_bounds__(256) void k_rowsq(const float* __restrict__ A,
                                               int nrows,
                                               float* __restrict__ out) {
  int r = blockIdx.x * 256 + threadIdx.x;
  if (r >= nrows) return;
  out[r] = np_pairwise_sq512(A + (size_t)r * D_IN);
}

// ---------------------------------------------------------------------------
// CBb = bf16(CB)
// ---------------------------------------------------------------------------
__global__ __launch_bounds__(256) void k_cb2bf(const float* __restrict__ CB,
                                               unsigned short* __restrict__ CBb) {
  int idx = (blockIdx.x * 256 + threadIdx.x) * 4;
  float4 v = *(const float4*)(CB + idx);
  ushort4 s;
  s.x = f2bf(v.x); s.y = f2bf(v.y); s.z = f2bf(v.z); s.w = f2bf(v.w);
  *(ushort4*)(CBb + idx) = s;
}

// ---------------------------------------------------------------------------
// H = X @ LP (np-exact fp32, single sequential-k FMA chain; verified r3).
// Also emits Hb = bf16(H) for the MFMA candidate pass.
// ---------------------------------------------------------------------------
__global__ __launch_bounds__(256) void k_h_np(const float* __restrict__ X,
                                              const float* __restrict__ W,
                                              float* __restrict__ H,
                                              unsigned short* __restrict__ Hb) {
  __shared__ float As[16][68];
  __shared__ float Bs[16][68];
  const int tid = threadIdx.x;
  const int row0 = blockIdx.x * 64;
  const int col0 = blockIdx.y * 64;
  const int ty = tid >> 4, tx = tid & 15;
  const int am = tid >> 2, ak = (tid & 3) << 2;
  const int bk = tid >> 4, bn = (tid & 15) << 2;
  float acc[4][4] = {};
  for (int k0 = 0; k0 < D_IN; k0 += 16) {
    float4 av = make_float4(0.f, 0.f, 0.f, 0.f);
    if (row0 + am < N_NODES)
      av = *(const float4*)(X + (size_t)(row0 + am) * D_IN + k0 + ak);
    float4 bv = *(const float4*)(W + (size_t)(k0 + bk) * D_IN + col0 + bn);
    __syncthreads();
    As[ak + 0][am] = av.x; As[ak + 1][am] = av.y;
    As[ak + 2][am] = av.z; As[ak + 3][am] = av.w;
    *(float4*)&Bs[bk][bn] = bv;
    __syncthreads();
#pragma unroll
    for (int kk = 0; kk < 16; kk++) {  // strictly increasing k
      float4 a = *(const float4*)&As[kk][ty << 2];
      float4 b = *(const float4*)&Bs[kk][tx << 2];
      float aa[4] = {a.x, a.y, a.z, a.w};
      float bb[4] = {b.x, b.y, b.z, b.w};
#pragma unroll
      for (int i = 0; i < 4; i++)
#pragma unroll
        for (int j = 0; j < 4; j++) acc[i][j] = fmaf(aa[i], bb[j], acc[i][j]);
    }
  }
#pragma unroll
  for (int i = 0; i < 4; i++) {
    int r = row0 + (ty << 2) + i;
    if (r < N_NODES) {
      *(float4*)(H + (size_t)r * D_IN + col0 + (tx << 2)) =
          make_float4(acc[i][0], acc[i][1], acc[i][2], acc[i][3]);
      ushort4 s;
      s.x = f2bf(acc[i][0]); s.y = f2bf(acc[i][1]);
      s.z = f2bf(acc[i][2]); s.w = f2bf(acc[i][3]);
      *(ushort4*)(Hb + (size_t)r * D_IN + col0 + (tx << 2)) = s;
    }
  }
}

// ---------------------------------------------------------------------------
// P[c][o] = CB[c]·HW[:,o] in fp64 (stored fp32). Logit path only.
// ---------------------------------------------------------------------------
__global__ __launch_bounds__(256) void k_gemm_P(const float* __restrict__ CB,
                                                const float* __restrict__ HW,
                                                float* __restrict__ P) {
  __shared__ float As[16][68];
  __shared__ float Bs[16][68];
  const int tid = threadIdx.x;
  const int c0 = blockIdx.x * 64;
  const int o0 = blockIdx.y * 64;
  const int ty = tid >> 4, tx = tid & 15;
  const int am = tid >> 2, ak = (tid & 3) << 2;
  const int bk = tid >> 4, bn = (tid & 15) << 2;
  double acc[4][4] = {};
  for (int k0 = 0; k0 < D_IN; k0 += 16) {
    float4 av = *(const float4*)(CB + (size_t)(c0 + am) * D_IN + k0 + ak);
    float4 bv = *(const float4*)(HW + (size_t)(k0 + bk) * D_OUT + o0 + bn);
    __syncthreads();
    As[ak + 0][am] = av.x; As[ak + 1][am] = av.y;
    As[ak + 2][am] = av.z; As[ak + 3][am] = av.w;
    *(float4*)&Bs[bk][bn] = bv;
    __syncthreads();
#pragma unroll
    for (int kk = 0; kk < 16; kk++) {
      float4 a = *(const float4*)&As[kk][ty << 2];
      float4 b = *(const float4*)&Bs[kk][tx << 2];
      double aa[4] = {a.x, a.y, a.z, a.w};
      double bb[4] = {b.x, b.y, b.z, b.w};
#pragma unroll
      for (int i = 0; i < 4; i++)
#pragma unroll
        for (int j = 0; j < 4; j++) acc[i][j] = fma(aa[i], bb[j], acc[i][j]);
    }
  }
#pragma unroll
  for (int i = 0; i < 4; i++)
#pragma unroll
    for (int j = 0; j < 4; j++)
      P[(size_t)(c0 + (ty << 2) + i) * D_OUT + o0 + (tx << 2) + j] =
          (float)acc[i][j];
}

// ---------------------------------------------------------------------------
// MFMA candidate pass v2: approx scores s = cbsq - 2*(Hb@CBb^T) over all 2048
// codes; per row keep running top-8 per 64-code half of each 128-tile.
// 128x128 tile; BK=64 DOUBLE-BUFFERED via global_load_lds width=16
// (direct HBM->LDS DMA, no VGPR round-trip). LDS layout stays swizzled
// (addr(row,chunk) = chunk*2048 + ((row+2*chunk)&127)*16) by PRE-SWIZZLING
// the per-lane GLOBAL source address: linear LDS cell (c, slot s) holds
// global row r = (s - 2c) & 127 (m173 pattern; gload_lds dest must be
// linear wave-uniform-base + lane*16).
// MFMA k-order identical to v1 (16 K=32 steps, increasing k) -> scores
// bit-identical -> selection/margin behavior unchanged.
// LDS union: { buf0 A16K|B16K buf1 A16K|B16K (64KB) | Sc[128][132] 67.6KB }.
// ---------------------------------------------------------------------------
__global__ __launch_bounds__(256, 2) void k_mfma_cand(
    const unsigned short* __restrict__ Hb,
    const unsigned short* __restrict__ CBb,
    const float* __restrict__ CBSQ,
    float* __restrict__ candS, int* __restrict__ candI) {
  __shared__ __align__(16) char LDS_RAW[67584];
  float* Sc = (float*)LDS_RAW;
  const int tid  = threadIdx.x;
  const int lane = tid & 63, wave = tid >> 6;
  const int quad = lane >> 4, l16 = lane & 15;
  const int wy = wave >> 1, wx = wave & 1;
  const int row0 = blockIdx.x * 128;
  const int srow = tid >> 1, shalf = tid & 1;

  // staging geometry: linear LDS slot id = tid + it*256 (it<4 per slab);
  // chunk c = id>>7 = (tid>>7) + 2*it, slot s = tid&127 (const per thread);
  // cell (c,s) holds global row r = (s - 2c) & 127.
  const int s_lin = tid & 127;
  const int c_hi  = tid >> 7;  // 0 or 1
  const unsigned woff = (unsigned)(wave << 10);  // wave*64*16: uniform base
  const char* pA[4];
  const char* pB[4];
#pragma unroll
  for (int it = 0; it < 4; it++) {
    int c = c_hi + 2 * it;
    int r = (s_lin - 2 * c) & 127;
    int ga = row0 + r;
    if (ga >= N_NODES) ga = 0;  // clamp: junk scores land only in dead rows
    pA[it] = (const char*)Hb + ((size_t)ga * D_IN + (size_t)c * 8) * 2;
    pB[it] = (const char*)CBb + ((size_t)r * D_IN + (size_t)c * 8) * 2;
  }

  float rs[8]; int ri[8];
#pragma unroll
  for (int k = 0; k < 8; k++) { rs[k] = 3.4e38f; ri[k] = 0x7fffffff; }

  for (int ct = 0; ct < NUM_CODES / 128; ct++) {
    const int code0 = ct * 128;
    const size_t cb_off = (size_t)code0 * D_IN * 2;  // bytes
    f32x4 acc[4][4];
#pragma unroll
    for (int rf = 0; rf < 4; rf++)
#pragma unroll
      for (int cf = 0; cf < 4; cf++)
        acc[rf][cf] = (f32x4){0.f, 0.f, 0.f, 0.f};

    __syncthreads();  // previous scan done -> slab region reusable
    // prologue: stage kb=0 into buf0 (8 x global_load_lds dwordx4)
#pragma unroll
    for (int it = 0; it < 4; it++) {
      gload16(pA[it], LDS_RAW + (it << 12) + woff);
      gload16(pB[it] + cb_off, LDS_RAW + 16384 + (it << 12) + woff);
    }
    for (int kb = 0; kb < 8; kb++) {  // BK = 64, double-buffered
      __syncthreads();  // buf[kb&1] staged (vmcnt drain) + prev reads done
      if (kb < 7) {     // issue next stage BEFORE compute (T3 minimum)
        const unsigned nb = (unsigned)(((kb + 1) & 1) << 15);
        const unsigned koff = (unsigned)((kb + 1) << 7);  // (kb+1)*64 elem *2B
#pragma unroll
        for (int it = 0; it < 4; it++) {
          gload16(pA[it] + koff, LDS_RAW + nb + (it << 12) + woff);
          gload16(pB[it] + cb_off + koff,
                  LDS_RAW + nb + 16384 + (it << 12) + woff);
        }
      }
      const char* bufA = LDS_RAW + ((kb & 1) << 15);
      const char* bufB = bufA + 16384;
#pragma unroll
      for (int s = 0; s < 2; s++) {  // 2 MFMA k-steps of 32
        int cidx = s * 4 + quad;
        bf16x8 af[4], bfr[4];
#pragma unroll
        for (int rf = 0; rf < 4; rf++) {
          int arow = wy * 64 + rf * 16 + l16;
          af[rf] = *(const bf16x8*)(bufA + cidx * 2048 +
                                    (((arow + 2 * cidx) & 127) << 4));
        }
#pragma unroll
        for (int cf = 0; cf < 4; cf++) {
          int brow = wx * 64 + cf * 16 + l16;
          bfr[cf] = *(const bf16x8*)(bufB + cidx * 2048 +
                                     (((brow + 2 * cidx) & 127) << 4));
        }
#pragma unroll
        for (int rf = 0; rf < 4; rf++)
#pragma unroll
          for (int cf = 0; cf < 4; cf++)
            acc[rf][cf] = __builtin_amdgcn_mfma_f32_16x16x32_bf16(
                af[rf], bfr[cf], acc[rf][cf], 0, 0, 0);
      }
    }
    __syncthreads();  // K done, slabs dead -> Sc region reusable
    // scores -> Sc[code][132]; C/D layout: col=lane&15, row=quad*4+reg
#pragma unroll
    for (int cf = 0; cf < 4; cf++) {
      int code = wx * 64 + cf * 16 + l16;
      float cq = CBSQ[code0 + code];
#pragma unroll
      for (int rf = 0; rf < 4; rf++) {
        f32x4 sv;
#pragma unroll
        for (int r = 0; r < 4; r++) sv[r] = fmaf(-2.0f, acc[rf][cf][r], cq);
        int rowb = wy * 64 + rf * 16 + quad * 4;
        *(f32x4*)(Sc + (size_t)code * 132 + rowb) = sv;
      }
    }
    __syncthreads();
    // scan: thread (srow, shalf) scans 64 codes of its half for its row
    for (int i = 0; i < 64; i++) {
      int cl = shalf * 64 + i;
      float s = Sc[(size_t)cl * 132 + srow];
      int c = code0 + cl;
      if (better(s, c, rs[7], ri[7])) {
        rs[7] = s; ri[7] = c;
#pragma unroll
        for (int t = 7; t > 0; t--) {
          if (better(rs[t], ri[t], rs[t - 1], ri[t - 1])) {
            float tf = rs[t - 1]; rs[t - 1] = rs[t]; rs[t] = tf;
            int tc = ri[t - 1]; ri[t - 1] = ri[t]; ri[t] = tc;
          }
        }
      }
    }
  }
  int grow = row0 + srow;
  if (grow < N_NODES) {
#pragma unroll
    for (int k = 0; k < 8; k++) {
      candS[(size_t)grow * NCAND + shalf * 8 + k] = rs[k];
      candI[(size_t)grow * NCAND + shalf * 8 + k] = ri[k];
    }
  }
}

// ---------------------------------------------------------------------------
// np-exact rescore of candidates within RESCORE_MARGIN of the 4th-best approx
// score; exact fp32 sequential-k chain + np combine; top-4 (ties->lower idx).
// Block: 16 rows x 16 candidates.
// ---------------------------------------------------------------------------
__global__ __launch_bounds__(256) void k_rescore(
    const float* __restrict__ H, const float* __restrict__ CB,
    const float* __restrict__ CBSQ, const float* __restrict__ HSQ,
    const float* __restrict__ candS, const int* __restrict__ candI,
    int* __restrict__ cand4) {
  __shared__ float hs[16][516];
  __shared__ float ss[16][16];
  __shared__ int   ii[16][16];
  __shared__ float sres[16][16];
  const int tid = threadIdx.x;
  const int r0 = blockIdx.x * 16;
#pragma unroll
  for (int it = 0; it < 8; it++) {  // 2048 float4 tasks: coop-load 16 H rows
    int id = tid + it * 256;
    int row = id >> 7, f4 = id & 127;
    float4 v = *(const float4*)(H + (size_t)(r0 + row) * D_IN + f4 * 4);
    *(float4*)&hs[row][f4 * 4] = v;
  }
  {
    int row = tid >> 4, j = tid & 15;
    ss[row][j] = candS[(size_t)(r0 + row) * NCAND + j];
    ii[row][j] = candI[(size_t)(r0 + row) * NCAND + j];
  }
  __syncthreads();
  const int row = tid >> 4, j = tid & 15;
  // 4th-smallest approx score of this row's 16 candidates
  float m[4] = {3.4e38f, 3.4e38f, 3.4e38f, 3.4e38f};
  for (int t = 0; t < 16; t++) {
    float s = ss[row][t];
    if (s < m[3]) {
      m[3] = s;
#pragma unroll
      for (int u = 3; u > 0; u--)
        if (m[u] < m[u - 1]) { float tt = m[u - 1]; m[u - 1] = m[u]; m[u] = tt; }
    }
  }
  const float thr = m[3] + RESCORE_MARGIN;
  const float as = ss[row][j];
  const int ci = ii[row][j];
  float sc = 3.4e38f;
  if (as <= thr) {
    const float4* cbp = (const float4*)(CB + (size_t)ci * D_IN);
    float d = 0.f;
    for (int k = 0; k < 128; k++) {  // strict k order: single FMA chain
      float4 c4 = cbp[k];
      float4 h4 = *(const float4*)&hs[row][k * 4];
      d = fmaf(h4.x, c4.x, d);
      d = fmaf(h4.y, c4.y, d);
      d = fmaf(h4.z, c4.z, d);
      d = fmaf(h4.w, c4.w, d);
    }
    float t1 = __fsub_rn(HSQ[r0 + row], 2.0f * d);  // 2*d exact
    sc = __fadd_rn(t1, CBSQ[ci]);                   // np combine order
  }
  sres[row][j] = sc;
  __syncthreads();
  if (j == 0) {
    float bs[4]; int bi[4];
#pragma unroll
    for (int k = 0; k < 4; k++) { bs[k] = 3.4e38f; bi[k] = 0x7fffffff; }
    for (int t = 0; t < 16; t++) {
      float s = sres[row][t]; int c = ii[row][t];
      if (better(s, c, bs[3], bi[3])) {
        bs[3] = s; bi[3] = c;
#pragma unroll
        for (int u = 3; u > 0; u--) {
          if (better(bs[u], bi[u], bs[u - 1], bi[u - 1])) {
            float tf = bs[u - 1]; bs[u - 1] = bs[u]; bs[u] = tf;
            int tc = bi[u - 1]; bi[u - 1] = bi[u]; bi[u] = tc;
          }
        }
      }
    }
#pragma unroll
    for (int k = 0; k < 4; k++) cand4[(size_t)(r0 + row) * 4 + k] = bi[k];
  }
}

// ---------------------------------------------------------------------------
// OUT[row] = 0.25 * (P[c0]+P[c1]+P[c2]+P[c3]) + bias. One wave per row.
// ---------------------------------------------------------------------------
__global__ __launch_bounds__(256) void k_out(const int* __restrict__ cand4,
                                             const float* __restrict__ P,
                                             const float* __restrict__ HB,
                                             float* __restrict__ OUT) {
  const int lane = threadIdx.x & 63;
  const int row = blockIdx.x * 4 + (threadIdx.x >> 6);
  if (row >= N_NODES) return;
  const int c0 = cand4[(size_t)row * 4 + 0];
  const int c1 = cand4[(size_t)row * 4 + 1];
  const int c2 = cand4[(size_t)row * 4 + 2];
  const int c3 = cand4[(size_t)row * 4 + 3];
  const int col = lane << 2;
  float4 p0 = *(const float4*)(P + (size_t)c0 * D_OUT + col);
  float4 p1 = *(const float4*)(P + (size_t)c1 * D_OUT + col);
  float4 p2 = *(const float4*)(P + (size_t)c2 * D_OUT + col);
  float4 p3 = *(const float4*)(P + (size_t)c3 * D_OUT + col);
  float4 b = *(const float4*)(HB + col);
  float4 o;
  o.x = 0.25f * (((p0.x + p1.x) + p2.x) + p3.x) + b.x;
  o.y = 0.25f * (((p0.y + p1.y) + p2.y) + p3.y) + b.y;
  o.z = 0.25f * (((p0.z + p1.z) + p2.z) + p3.z) + b.z;
  o.w = 0.25f * (((p0.w + p1.w) + p2.w) + p3.w) + b.w;
  *(float4*)(OUT + (size_t)row * D_OUT + col) = o;
}

// ---------------------------------------------------------------------------
extern "C" void kernel_launch(void* const* d_in, const int* in_sizes, int n_in,
                              void* d_out, int out_size, void* d_ws,
                              size_t ws_size, hipStream_t stream) {
  const float* X  = (const float*)d_in[0];
  const float* LP = (const float*)d_in[1];
  const float* CB = (const float*)d_in[2];
  const float* HW = (const float*)d_in[3];
  const float* HB = (const float*)d_in[4];
  float* OUT = (float*)d_out;

  // d_out (100000*256*4 B) doubles as Hb (100000*512*2 B bf16, exact fit);
  // Hb fully consumed by k_mfma_cand before k_out overwrites.
  unsigned short* Hb = (unsigned short*)d_out;

  char* ws = (char*)d_ws;
  size_t off = 0;
  float* H = (float*)(ws + off);      off += (size_t)N_NODES * D_IN * 4;     // 204.8 MB
  float* P = (float*)(ws + off);      off += (size_t)NUM_CODES * D_OUT * 4;  // 2 MB
  unsigned short* CBb = (unsigned short*)(ws + off);
  off += (size_t)NUM_CODES * D_IN * 2;                                       // 2 MB
  float* CBSQ = (float*)(ws + off);   off += (size_t)NUM_CODES * 4;
  float* HSQ = (float*)(ws + off);    off += (size_t)N_NODES * 4;
  off = (off + 255) & ~(size_t)255;
  float* candS = (float*)(ws + off);  off += (size_t)N_NODES * NCAND * 4;    // 6.4 MB
  int* candI = (int*)(ws + off);      off += (size_t)N_NODES * NCAND * 4;    // 6.4 MB
  int* cand4 = (int*)(ws + off);      off += (size_t)N_NODES * 4 * 4;        // 1.6 MB
  // total ~224 MB

  const int row64 = (N_NODES + 63) / 64;
  const int row128 = (N_NODES + 127) / 128;

  k_rowsq<<<(NUM_CODES + 255) / 256, 256, 0, stream>>>(CB, NUM_CODES, CBSQ);
  k_cb2bf<<<NUM_CODES * D_IN / 1024, 256, 0, stream>>>(CB, CBb);
  k_gemm_P<<<dim3(NUM_CODES / 64, D_OUT / 64), 256, 0, stream>>>(CB, HW, P);
  k_h_np<<<dim3(row64, D_IN / 64), 256, 0, stream>>>(X, LP, H, Hb);
  k_rowsq<<<(N_NODES + 255) / 256, 256, 0, stream>>>(H, N_NODES, HSQ);
  k_mfma_cand<<<row128, 256, 0, stream>>>(Hb, CBb, CBSQ, candS, candI);
  k_rescore<<<N_NODES / 16, 256, 0, stream>>>(H, CB, CBSQ, HSQ, candS, candI,
                                              cand4);
  k_out<<<N_NODES / 4, 256, 0, stream>>>(cand4, P, HB, OUT);
}

// Round 3
// 2495.254 us; speedup vs baseline: 1.0460x; 1.0405x over previous
//
#include <hip/hip_runtime.h>

#define N_NODES   100000
#define D_IN      512
#define NUM_CODES 2048
#define D_OUT     256
#define NCAND     16
#define RESCORE_MARGIN 0.05f

typedef float f32x4  __attribute__((ext_vector_type(4)));
typedef short bf16x8 __attribute__((ext_vector_type(8)));

__device__ __forceinline__ bool better(float s, int i, float S, int I) {
  return (s < S) || (s == S && i < I);
}

__device__ __forceinline__ unsigned short f2bf(float f) {
  unsigned int u = __float_as_uint(f);
  u = (u + 0x7fffu + ((u >> 16) & 1u)) >> 16;  // RNE
  return (unsigned short)u;
}

// async global->LDS, 16B per lane; lds ptr must be the wave-uniform base
// (HW writes lane i at base + i*16).
typedef const __attribute__((address_space(1))) unsigned int* gas_ptr;
typedef __attribute__((address_space(3))) unsigned int* las_ptr;
__device__ __forceinline__ void gload16(const void* g, void* l) {
  __builtin_amdgcn_global_load_lds((gas_ptr)g, (las_ptr)l, 16, 0, 0);
}

// ---------------------------------------------------------------------------
// numpy pairwise sum-of-squares over a 512-float row (np-exact; see r3).
// ---------------------------------------------------------------------------
__device__ __forceinline__ float np_pairwise_sq512(const float* __restrict__ a) {
  float tot[4];
#pragma unroll
  for (int b = 0; b < 4; b++) {
    const float* p = a + (b << 7);
    float r[8];
    {
      float4 q0 = *(const float4*)(p);
      float4 q1 = *(const float4*)(p + 4);
      r[0] = __fmul_rn(q0.x, q0.x); r[1] = __fmul_rn(q0.y, q0.y);
      r[2] = __fmul_rn(q0.z, q0.z); r[3] = __fmul_rn(q0.w, q0.w);
      r[4] = __fmul_rn(q1.x, q1.x); r[5] = __fmul_rn(q1.y, q1.y);
      r[6] = __fmul_rn(q1.z, q1.z); r[7] = __fmul_rn(q1.w, q1.w);
    }
    for (int i = 8; i < 128; i += 8) {
      float4 u0 = *(const float4*)(p + i);
      float4 u1 = *(const float4*)(p + i + 4);
      r[0] = __fadd_rn(r[0], __fmul_rn(u0.x, u0.x));
      r[1] = __fadd_rn(r[1], __fmul_rn(u0.y, u0.y));
      r[2] = __fadd_rn(r[2], __fmul_rn(u0.z, u0.z));
      r[3] = __fadd_rn(r[3], __fmul_rn(u0.w, u0.w));
      r[4] = __fadd_rn(r[4], __fmul_rn(u1.x, u1.x));
      r[5] = __fadd_rn(r[5], __fmul_rn(u1.y, u1.y));
      r[6] = __fadd_rn(r[6], __fmul_rn(u1.z, u1.z));
      r[7] = __fadd_rn(r[7], __fmul_rn(u1.w, u1.w));
    }
    float t01 = __fadd_rn(r[0], r[1]);
    float t23 = __fadd_rn(r[2], r[3]);
    float t45 = __fadd_rn(r[4], r[5]);
    float t67 = __fadd_rn(r[6], r[7]);
    tot[b] = __fadd_rn(__fadd_rn(t01, t23), __fadd_rn(t45, t67));
  }
  return __fadd_rn(__fadd_rn(tot[0], tot[1]), __fadd_rn(tot[2], tot[3]));
}

__global__ __launch_bounds__(256) void k_rowsq(const float* __restrict__ A,
                                               int nrows,
                                               float* __restrict__ out) {
  int r = blockIdx.x * 256 + threadIdx.x;
  if (r >= nrows) return;
  out[r] = np_pairwise_sq512(A + (size_t)r * D_IN);
}

// ---------------------------------------------------------------------------
// CBb = bf16(CB)
// ---------------------------------------------------------------------------
__global__ __launch_bounds__(256) void k_cb2bf(const float* __restrict__ CB,
                                               unsigned short* __restrict__ CBb) {
  int idx = (blockIdx.x * 256 + threadIdx.x) * 4;
  float4 v = *(const float4*)(CB + idx);
  ushort4 s;
  s.x = f2bf(v.x); s.y = f2bf(v.y); s.z = f2bf(v.z); s.w = f2bf(v.w);
  *(ushort4*)(CBb + idx) = s;
}

// ---------------------------------------------------------------------------
// H = X @ LP (np-exact fp32, single sequential-k FMA chain; verified r3).
// Also emits Hb = bf16(H) for the MFMA candidate pass.
// ---------------------------------------------------------------------------
__global__ __launch_bounds__(256) void k_h_np(const float* __restrict__ X,
                                              const float* __restrict__ W,
                                              float* __restrict__ H,
                                              unsigned short* __restrict__ Hb) {
  __shared__ float As[16][68];
  __shared__ float Bs[16][68];
  const int tid = threadIdx.x;
  const int row0 = blockIdx.x * 64;
  const int col0 = blockIdx.y * 64;
  const int ty = tid >> 4, tx = tid & 15;
  const int am = tid >> 2, ak = (tid & 3) << 2;
  const int bk = tid >> 4, bn = (tid & 15) << 2;
  float acc[4][4] = {};
  for (int k0 = 0; k0 < D_IN; k0 += 16) {
    float4 av = make_float4(0.f, 0.f, 0.f, 0.f);
    if (row0 + am < N_NODES)
      av = *(const float4*)(X + (size_t)(row0 + am) * D_IN + k0 + ak);
    float4 bv = *(const float4*)(W + (size_t)(k0 + bk) * D_IN + col0 + bn);
    __syncthreads();
    As[ak + 0][am] = av.x; As[ak + 1][am] = av.y;
    As[ak + 2][am] = av.z; As[ak + 3][am] = av.w;
    *(float4*)&Bs[bk][bn] = bv;
    __syncthreads();
#pragma unroll
    for (int kk = 0; kk < 16; kk++) {  // strictly increasing k
      float4 a = *(const float4*)&As[kk][ty << 2];
      float4 b = *(const float4*)&Bs[kk][tx << 2];
      float aa[4] = {a.x, a.y, a.z, a.w};
      float bb[4] = {b.x, b.y, b.z, b.w};
#pragma unroll
      for (int i = 0; i < 4; i++)
#pragma unroll
        for (int j = 0; j < 4; j++) acc[i][j] = fmaf(aa[i], bb[j], acc[i][j]);
    }
  }
#pragma unroll
  for (int i = 0; i < 4; i++) {
    int r = row0 + (ty << 2) + i;
    if (r < N_NODES) {
      *(float4*)(H + (size_t)r * D_IN + col0 + (tx << 2)) =
          make_float4(acc[i][0], acc[i][1], acc[i][2], acc[i][3]);
      ushort4 s;
      s.x = f2bf(acc[i][0]); s.y = f2bf(acc[i][1]);
      s.z = f2bf(acc[i][2]); s.w = f2bf(acc[i][3]);
      *(ushort4*)(Hb + (size_t)r * D_IN + col0 + (tx << 2)) = s;
    }
  }
}

// ---------------------------------------------------------------------------
// P[c][o] = CB[c]·HW[:,o] in fp64 (stored fp32). Logit path only.
// ---------------------------------------------------------------------------
__global__ __launch_bounds__(256) void k_gemm_P(const float* __restrict__ CB,
                                                const float* __restrict__ HW,
                                                float* __restrict__ P) {
  __shared__ float As[16][68];
  __shared__ float Bs[16][68];
  const int tid = threadIdx.x;
  const int c0 = blockIdx.x * 64;
  const int o0 = blockIdx.y * 64;
  const int ty = tid >> 4, tx = tid & 15;
  const int am = tid >> 2, ak = (tid & 3) << 2;
  const int bk = tid >> 4, bn = (tid & 15) << 2;
  double acc[4][4] = {};
  for (int k0 = 0; k0 < D_IN; k0 += 16) {
    float4 av = *(const float4*)(CB + (size_t)(c0 + am) * D_IN + k0 + ak);
    float4 bv = *(const float4*)(HW + (size_t)(k0 + bk) * D_OUT + o0 + bn);
    __syncthreads();
    As[ak + 0][am] = av.x; As[ak + 1][am] = av.y;
    As[ak + 2][am] = av.z; As[ak + 3][am] = av.w;
    *(float4*)&Bs[bk][bn] = bv;
    __syncthreads();
#pragma unroll
    for (int kk = 0; kk < 16; kk++) {
      float4 a = *(const float4*)&As[kk][ty << 2];
      float4 b = *(const float4*)&Bs[kk][tx << 2];
      double aa[4] = {a.x, a.y, a.z, a.w};
      double bb[4] = {b.x, b.y, b.z, b.w};
#pragma unroll
      for (int i = 0; i < 4; i++)
#pragma unroll
        for (int j = 0; j < 4; j++) acc[i][j] = fma(aa[i], bb[j], acc[i][j]);
    }
  }
#pragma unroll
  for (int i = 0; i < 4; i++)
#pragma unroll
    for (int j = 0; j < 4; j++)
      P[(size_t)(c0 + (ty << 2) + i) * D_OUT + o0 + (tx << 2) + j] =
          (float)acc[i][j];
}

// ---------------------------------------------------------------------------
// MFMA candidate pass v3: kb-loop identical to v2 (BK=64 dbuf via
// global_load_lds w=16, pre-swizzled global source, swizzled LDS slabs).
// Score/scan phase:
//   Sc transposed to [row][128] f32 (stride 512B, 64KB) with 3-bit XOR
//   group-swizzle p = (g&24)|((g^row)&7)  (g = code>>2 within tile) so
//   scalar score-writes and f32x4 scan-reads are <=2-way bank conflicts.
//   Scan: 16 independent ds_read_b128 preloaded to registers (one latency
//   exposure per ct instead of 64 serial scalar reads), min-based 4-wide
//   group reject, insertion only on group hit. Codes visited in ascending
//   order + strict < insertion == old (score,idx) lexicographic selection.
//   Candidate lists bit-identical to v1/v2.
// LDS union: { buf0 A16K|B16K buf1 A16K|B16K (64KB) | ScT[128][128] 64KB }.
// ---------------------------------------------------------------------------
__global__ __launch_bounds__(256, 2) void k_mfma_cand(
    const unsigned short* __restrict__ Hb,
    const unsigned short* __restrict__ CBb,
    const float* __restrict__ CBSQ,
    float* __restrict__ candS, int* __restrict__ candI) {
  __shared__ __align__(16) char LDS_RAW[65536];
  float* Sc = (float*)LDS_RAW;
  const int tid  = threadIdx.x;
  const int lane = tid & 63, wave = tid >> 6;
  const int quad = lane >> 4, l16 = lane & 15;
  const int wy = wave >> 1, wx = wave & 1;
  const int row0 = blockIdx.x * 128;
  const int srow = tid >> 1, shalf = tid & 1;

  // staging geometry: linear LDS slot id = tid + it*256 (it<4 per slab);
  // chunk c = (tid>>7) + 2*it, slot s = tid&127 (const per thread);
  // cell (c,s) holds global row r = (s - 2c) & 127.
  const int s_lin = tid & 127;
  const int c_hi  = tid >> 7;  // 0 or 1
  const unsigned woff = (unsigned)(wave << 10);  // wave*64*16: uniform base
  const char* pA[4];
  const char* pB[4];
#pragma unroll
  for (int it = 0; it < 4; it++) {
    int c = c_hi + 2 * it;
    int r = (s_lin - 2 * c) & 127;
    int ga = row0 + r;
    if (ga >= N_NODES) ga = 0;  // clamp: junk scores land only in dead rows
    pA[it] = (const char*)Hb + ((size_t)ga * D_IN + (size_t)c * 8) * 2;
    pB[it] = (const char*)CBb + ((size_t)r * D_IN + (size_t)c * 8) * 2;
  }

  float rs[8]; int ri[8];
#pragma unroll
  for (int k = 0; k < 8; k++) { rs[k] = 3.4e38f; ri[k] = 0x7fffffff; }

  for (int ct = 0; ct < NUM_CODES / 128; ct++) {
    const int code0 = ct * 128;
    const size_t cb_off = (size_t)code0 * D_IN * 2;  // bytes
    f32x4 acc[4][4];
#pragma unroll
    for (int rf = 0; rf < 4; rf++)
#pragma unroll
      for (int cf = 0; cf < 4; cf++)
        acc[rf][cf] = (f32x4){0.f, 0.f, 0.f, 0.f};

    __syncthreads();  // previous scan done -> slab region reusable
    // prologue: stage kb=0 into buf0 (8 x global_load_lds dwordx4)
#pragma unroll
    for (int it = 0; it < 4; it++) {
      gload16(pA[it], LDS_RAW + (it << 12) + woff);
      gload16(pB[it] + cb_off, LDS_RAW + 16384 + (it << 12) + woff);
    }
    for (int kb = 0; kb < 8; kb++) {  // BK = 64, double-buffered
      __syncthreads();  // buf[kb&1] staged (vmcnt drain) + prev reads done
      if (kb < 7) {     // issue next stage BEFORE compute
        const unsigned nb = (unsigned)(((kb + 1) & 1) << 15);
        const unsigned koff = (unsigned)((kb + 1) << 7);  // (kb+1)*64 elem *2B
#pragma unroll
        for (int it = 0; it < 4; it++) {
          gload16(pA[it] + koff, LDS_RAW + nb + (it << 12) + woff);
          gload16(pB[it] + cb_off + koff,
                  LDS_RAW + nb + 16384 + (it << 12) + woff);
        }
      }
      const char* bufA = LDS_RAW + ((kb & 1) << 15);
      const char* bufB = bufA + 16384;
#pragma unroll
      for (int s = 0; s < 2; s++) {  // 2 MFMA k-steps of 32
        int cidx = s * 4 + quad;
        bf16x8 af[4], bfr[4];
#pragma unroll
        for (int rf = 0; rf < 4; rf++) {
          int arow = wy * 64 + rf * 16 + l16;
          af[rf] = *(const bf16x8*)(bufA + cidx * 2048 +
                                    (((arow + 2 * cidx) & 127) << 4));
        }
#pragma unroll
        for (int cf = 0; cf < 4; cf++) {
          int brow = wx * 64 + cf * 16 + l16;
          bfr[cf] = *(const bf16x8*)(bufB + cidx * 2048 +
                                     (((brow + 2 * cidx) & 127) << 4));
        }
#pragma unroll
        for (int rf = 0; rf < 4; rf++)
#pragma unroll
          for (int cf = 0; cf < 4; cf++)
            acc[rf][cf] = __builtin_amdgcn_mfma_f32_16x16x32_bf16(
                af[rf], bfr[cf], acc[rf][cf], 0, 0, 0);
      }
    }
    __syncthreads();  // K done, slabs dead -> ScT region reusable
    // scores -> ScT[row][128], group-swizzled. C/D: col=lane&15, row=quad*4+r
#pragma unroll
    for (int cf = 0; cf < 4; cf++) {
      int code = wx * 64 + cf * 16 + l16;
      float cq = CBSQ[code0 + code];
      int g = code >> 2;
      int e = code & 3;
#pragma unroll
      for (int rf = 0; rf < 4; rf++) {
        int rowb = wy * 64 + rf * 16 + quad * 4;
#pragma unroll
        for (int r = 0; r < 4; r++) {
          float s = fmaf(-2.0f, acc[rf][cf][r], cq);
          int row = rowb + r;
          int p = (g & 24) | ((g ^ row) & 7);
          Sc[(size_t)row * 128 + (p << 2) + e] = s;
        }
      }
    }
    __syncthreads();
    // scan: thread (srow, shalf): preload 16 f32x4 (visit-swizzled), then
    // min group-reject + insertion (strict <, ascending code order).
    f32x4 vv[16];
    const float* rowbase = Sc + (size_t)srow * 128;
#pragma unroll
    for (int j = 0; j < 16; j++) {
      int g = shalf * 16 + j;
      int p = (g & 24) | ((g ^ srow) & 7);
      vv[j] = *(const f32x4*)(rowbase + (p << 2));
    }
#pragma unroll
    for (int j = 0; j < 16; j++) {
      f32x4 v = vv[j];
      float mn = fminf(fminf(v[0], v[1]), fminf(v[2], v[3]));
      if (mn < rs[7]) {
        int cb = code0 + shalf * 64 + (j << 2);
#pragma unroll
        for (int e = 0; e < 4; e++) {
          if (v[e] < rs[7]) {
            rs[7] = v[e]; ri[7] = cb + e;
#pragma unroll
            for (int t = 7; t > 0; t--) {
              if (rs[t] < rs[t - 1]) {
                float tf = rs[t - 1]; rs[t - 1] = rs[t]; rs[t] = tf;
                int tc = ri[t - 1]; ri[t - 1] = ri[t]; ri[t] = tc;
              }
            }
          }
        }
      }
    }
  }
  int grow = row0 + srow;
  if (grow < N_NODES) {
#pragma unroll
    for (int k = 0; k < 8; k++) {
      candS[(size_t)grow * NCAND + shalf * 8 + k] = rs[k];
      candI[(size_t)grow * NCAND + shalf * 8 + k] = ri[k];
    }
  }
}

// ---------------------------------------------------------------------------
// np-exact rescore of candidates within RESCORE_MARGIN of the 4th-best approx
// score; exact fp32 sequential-k chain + np combine; top-4 (ties->lower idx).
// Block: 16 rows x 16 candidates.
// ---------------------------------------------------------------------------
__global__ __launch_bounds__(256) void k_rescore(
    const float* __restrict__ H, const float* __restrict__ CB,
    const float* __restrict__ CBSQ, const float* __restrict__ HSQ,
    const float* __restrict__ candS, const int* __restrict__ candI,
    int* __restrict__ cand4) {
  __shared__ float hs[16][516];
  __shared__ float ss[16][16];
  __shared__ int   ii[16][16];
  __shared__ float sres[16][16];
  const int tid = threadIdx.x;
  const int r0 = blockIdx.x * 16;
#pragma unroll
  for (int it = 0; it < 8; it++) {  // 2048 float4 tasks: coop-load 16 H rows
    int id = tid + it * 256;
    int row = id >> 7, f4 = id & 127;
    float4 v = *(const float4*)(H + (size_t)(r0 + row) * D_IN + f4 * 4);
    *(float4*)&hs[row][f4 * 4] = v;
  }
  {
    int row = tid >> 4, j = tid & 15;
    ss[row][j] = candS[(size_t)(r0 + row) * NCAND + j];
    ii[row][j] = candI[(size_t)(r0 + row) * NCAND + j];
  }
  __syncthreads();
  const int row = tid >> 4, j = tid & 15;
  // 4th-smallest approx score of this row's 16 candidates
  float m[4] = {3.4e38f, 3.4e38f, 3.4e38f, 3.4e38f};
  for (int t = 0; t < 16; t++) {
    float s = ss[row][t];
    if (s < m[3]) {
      m[3] = s;
#pragma unroll
      for (int u = 3; u > 0; u--)
        if (m[u] < m[u - 1]) { float tt = m[u - 1]; m[u - 1] = m[u]; m[u] = tt; }
    }
  }
  const float thr = m[3] + RESCORE_MARGIN;
  const float as = ss[row][j];
  const int ci = ii[row][j];
  float sc = 3.4e38f;
  if (as <= thr) {
    const float4* cbp = (const float4*)(CB + (size_t)ci * D_IN);
    float d = 0.f;
    for (int k = 0; k < 128; k++) {  // strict k order: single FMA chain
      float4 c4 = cbp[k];
      float4 h4 = *(const float4*)&hs[row][k * 4];
      d = fmaf(h4.x, c4.x, d);
      d = fmaf(h4.y, c4.y, d);
      d = fmaf(h4.z, c4.z, d);
      d = fmaf(h4.w, c4.w, d);
    }
    float t1 = __fsub_rn(HSQ[r0 + row], 2.0f * d);  // 2*d exact
    sc = __fadd_rn(t1, CBSQ[ci]);                   // np combine order
  }
  sres[row][j] = sc;
  __syncthreads();
  if (j == 0) {
    float bs[4]; int bi[4];
#pragma unroll
    for (int k = 0; k < 4; k++) { bs[k] = 3.4e38f; bi[k] = 0x7fffffff; }
    for (int t = 0; t < 16; t++) {
      float s = sres[row][t]; int c = ii[row][t];
      if (better(s, c, bs[3], bi[3])) {
        bs[3] = s; bi[3] = c;
#pragma unroll
        for (int u = 3; u > 0; u--) {
          if (better(bs[u], bi[u], bs[u - 1], bi[u - 1])) {
            float tf = bs[u - 1]; bs[u - 1] = bs[u]; bs[u] = tf;
            int tc = bi[u - 1]; bi[u - 1] = bi[u]; bi[u] = tc;
          }
        }
      }
    }
#pragma unroll
    for (int k = 0; k < 4; k++) cand4[(size_t)(r0 + row) * 4 + k] = bi[k];
  }
}

// ---------------------------------------------------------------------------
// OUT[row] = 0.25 * (P[c0]+P[c1]+P[c2]+P[c3]) + bias. One wave per row.
// ---------------------------------------------------------------------------
__global__ __launch_bounds__(256) void k_out(const int* __restrict__ cand4,
                                             const float* __restrict__ P,
                                             const float* __restrict__ HB,
                                             float* __restrict__ OUT) {
  const int lane = threadIdx.x & 63;
  const int row = blockIdx.x * 4 + (threadIdx.x >> 6);
  if (row >= N_NODES) return;
  const int c0 = cand4[(size_t)row * 4 + 0];
  const int c1 = cand4[(size_t)row * 4 + 1];
  const int c2 = cand4[(size_t)row * 4 + 2];
  const int c3 = cand4[(size_t)row * 4 + 3];
  const int col = lane << 2;
  float4 p0 = *(const float4*)(P + (size_t)c0 * D_OUT + col);
  float4 p1 = *(const float4*)(P + (size_t)c1 * D_OUT + col);
  float4 p2 = *(const float4*)(P + (size_t)c2 * D_OUT + col);
  float4 p3 = *(const float4*)(P + (size_t)c3 * D_OUT + col);
  float4 b = *(const float4*)(HB + col);
  float4 o;
  o.x = 0.25f * (((p0.x + p1.x) + p2.x) + p3.x) + b.x;
  o.y = 0.25f * (((p0.y + p1.y) + p2.y) + p3.y) + b.y;
  o.z = 0.25f * (((p0.z + p1.z) + p2.z) + p3.z) + b.z;
  o.w = 0.25f * (((p0.w + p1.w) + p2.w) + p3.w) + b.w;
  *(float4*)(OUT + (size_t)row * D_OUT + col) = o;
}

// ---------------------------------------------------------------------------
extern "C" void kernel_launch(void* const* d_in, const int* in_sizes, int n_in,
                              void* d_out, int out_size, void* d_ws,
                              size_t ws_size, hipStream_t stream) {
  const float* X  = (const float*)d_in[0];
  const float* LP = (const float*)d_in[1];
  const float* CB = (const float*)d_in[2];
  const float* HW = (const float*)d_in[3];
  const float* HB = (const float*)d_in[4];
  float* OUT = (float*)d_out;

  // d_out (100000*256*4 B) doubles as Hb (100000*512*2 B bf16, exact fit);
  // Hb fully consumed by k_mfma_cand before k_out overwrites.
  unsigned short* Hb = (unsigned short*)d_out;

  char* ws = (char*)d_ws;
  size_t off = 0;
  float* H = (float*)(ws + off);      off += (size_t)N_NODES * D_IN * 4;     // 204.8 MB
  float* P = (float*)(ws + off);      off += (size_t)NUM_CODES * D_OUT * 4;  // 2 MB
  unsigned short* CBb = (unsigned short*)(ws + off);
  off += (size_t)NUM_CODES * D_IN * 2;                                       // 2 MB
  float* CBSQ = (float*)(ws + off);   off += (size_t)NUM_CODES * 4;
  float* HSQ = (float*)(ws + off);    off += (size_t)N_NODES * 4;
  off = (off + 255) & ~(size_t)255;
  float* candS = (float*)(ws + off);  off += (size_t)N_NODES * NCAND * 4;    // 6.4 MB
  int* candI = (int*)(ws + off);      off += (size_t)N_NODES * NCAND * 4;    // 6.4 MB
  int* cand4 = (int*)(ws + off);      off += (size_t)N_NODES * 4 * 4;        // 1.6 MB
  // total ~224 MB

  const int row64 = (N_NODES + 63) / 64;
  const int row128 = (N_NODES + 127) / 128;

  k_rowsq<<<(NUM_CODES + 255) / 256, 256, 0, stream>>>(CB, NUM_CODES, CBSQ);
  k_cb2bf<<<NUM_CODES * D_IN / 1024, 256, 0, stream>>>(CB, CBb);
  k_gemm_P<<<dim3(NUM_CODES / 64, D_OUT / 64), 256, 0, stream>>>(CB, HW, P);
  k_h_np<<<dim3(row64, D_IN / 64), 256, 0, stream>>>(X, LP, H, Hb);
  k_rowsq<<<(N_NODES + 255) / 256, 256, 0, stream>>>(H, N_NODES, HSQ);
  k_mfma_cand<<<row128, 256, 0, stream>>>(Hb, CBb, CBSQ, candS, candI);
  k_rescore<<<N_NODES / 16, 256, 0, stream>>>(H, CB, CBSQ, HSQ, candS, candI,
                                              cand4);
  k_out<<<N_NODES / 4, 256, 0, stream>>>(cand4, P, HB, OUT);
}

// Round 5
// 2115.930 us; speedup vs baseline: 1.2335x; 1.1793x over previous
//
#include <hip/hip_runtime.h>

#define N_NODES   100000
#define D_IN      512
#define NUM_CODES 2048
#define D_OUT     256
#define NCAND     16
#define RESCORE_MARGIN 0.05f
#define TSPLIT    780   // packed-Hb tiles [0,780) in d_out, [780,782) in ws tail

typedef float f32x4  __attribute__((ext_vector_type(4)));
typedef short bf16x8 __attribute__((ext_vector_type(8)));

__device__ __forceinline__ bool better(float s, int i, float S, int I) {
  return (s < S) || (s == S && i < I);
}

__device__ __forceinline__ unsigned short f2bf(float f) {
  unsigned int u = __float_as_uint(f);
  u = (u + 0x7fffu + ((u >> 16) & 1u)) >> 16;  // RNE
  return (unsigned short)u;
}

// async global->LDS, 16B per lane; lds ptr must be the wave-uniform base
// (HW writes lane i at base + i*16).
typedef const __attribute__((address_space(1))) unsigned int* gas_ptr;
typedef __attribute__((address_space(3))) unsigned int* las_ptr;
__device__ __forceinline__ void gload16(const void* g, void* l) {
  __builtin_amdgcn_global_load_lds((gas_ptr)g, (las_ptr)l, 16, 0, 0);
}

// packed-swizzled tile layout (both Hb and CBb):
//   tile t (128 rows), K-block kb (64 elems), chunk c (8 elems), row r:
//   byte = t*131072 + kb*16384 + c*2048 + ((r+2c)&127)*16
// == the LDS slab image; staging becomes contiguous-global -> linear-LDS.

// ---------------------------------------------------------------------------
// numpy pairwise sum-of-squares over a 512-float row (np-exact; see r3).
// ---------------------------------------------------------------------------
__device__ __forceinline__ float np_pairwise_sq512(const float* __restrict__ a) {
  float tot[4];
#pragma unroll
  for (int b = 0; b < 4; b++) {
    const float* p = a + (b << 7);
    float r[8];
    {
      float4 q0 = *(const float4*)(p);
      float4 q1 = *(const float4*)(p + 4);
      r[0] = __fmul_rn(q0.x, q0.x); r[1] = __fmul_rn(q0.y, q0.y);
      r[2] = __fmul_rn(q0.z, q0.z); r[3] = __fmul_rn(q0.w, q0.w);
      r[4] = __fmul_rn(q1.x, q1.x); r[5] = __fmul_rn(q1.y, q1.y);
      r[6] = __fmul_rn(q1.z, q1.z); r[7] = __fmul_rn(q1.w, q1.w);
    }
    for (int i = 8; i < 128; i += 8) {
      float4 u0 = *(const float4*)(p + i);
      float4 u1 = *(const float4*)(p + i + 4);
      r[0] = __fadd_rn(r[0], __fmul_rn(u0.x, u0.x));
      r[1] = __fadd_rn(r[1], __fmul_rn(u0.y, u0.y));
      r[2] = __fadd_rn(r[2], __fmul_rn(u0.z, u0.z));
      r[3] = __fadd_rn(r[3], __fmul_rn(u0.w, u0.w));
      r[4] = __fadd_rn(r[4], __fmul_rn(u1.x, u1.x));
      r[5] = __fadd_rn(r[5], __fmul_rn(u1.y, u1.y));
      r[6] = __fadd_rn(r[6], __fmul_rn(u1.z, u1.z));
      r[7] = __fadd_rn(r[7], __fmul_rn(u1.w, u1.w));
    }
    float t01 = __fadd_rn(r[0], r[1]);
    float t23 = __fadd_rn(r[2], r[3]);
    float t45 = __fadd_rn(r[4], r[5]);
    float t67 = __fadd_rn(r[6], r[7]);
    tot[b] = __fadd_rn(__fadd_rn(t01, t23), __fadd_rn(t45, t67));
  }
  return __fadd_rn(__fadd_rn(tot[0], tot[1]), __fadd_rn(tot[2], tot[3]));
}

__global__ __launch_bounds__(256) void k_rowsq(const float* __restrict__ A,
                                               int nrows,
                                               float* __restrict__ out) {
  int r = blockIdx.x * 256 + threadIdx.x;
  if (r >= nrows) return;
  out[r] = np_pairwise_sq512(A + (size_t)r * D_IN);
}

// ---------------------------------------------------------------------------
// CBb_sw = bf16(CB) in packed-swizzled tile layout. 131072 cells of 16B.
// ---------------------------------------------------------------------------
__global__ __launch_bounds__(256) void k_cb2bf(const float* __restrict__ CB,
                                               char* __restrict__ CBb_sw) {
  int id = blockIdx.x * 256 + threadIdx.x;  // [0, 131072)
  int code = id >> 6, cell = id & 63;
  int kb = cell >> 3, c = cell & 7;
  int ct = code >> 7, rr = code & 127;
  const float* src = CB + (size_t)code * D_IN + (cell << 3);
  float4 v0 = *(const float4*)src;
  float4 v1 = *(const float4*)(src + 4);
  unsigned int w0 = (unsigned)f2bf(v0.x) | ((unsigned)f2bf(v0.y) << 16);
  unsigned int w1 = (unsigned)f2bf(v0.z) | ((unsigned)f2bf(v0.w) << 16);
  unsigned int w2 = (unsigned)f2bf(v1.x) | ((unsigned)f2bf(v1.y) << 16);
  unsigned int w3 = (unsigned)f2bf(v1.z) | ((unsigned)f2bf(v1.w) << 16);
  *(uint4*)(CBb_sw + (size_t)(ct * 8 + kb) * 16384 + c * 2048 +
            (((rr + 2 * c) & 127) << 4)) = make_uint4(w0, w1, w2, w3);
}

// ---------------------------------------------------------------------------
// H = X @ LP (np-exact fp32, single sequential-k FMA chain; verified r3).
// Also emits packed-swizzled bf16(H) for the MFMA candidate pass.
// ---------------------------------------------------------------------------
__global__ __launch_bounds__(256) void k_h_np(const float* __restrict__ X,
                                              const float* __restrict__ W,
                                              float* __restrict__ H,
                                              char* __restrict__ HbMain,
                                              char* __restrict__ HbTail) {
  __shared__ float As[16][68];
  __shared__ float Bs[16][68];
  const int tid = threadIdx.x;
  const int row0 = blockIdx.x * 64;
  const int col0 = blockIdx.y * 64;
  const int ty = tid >> 4, tx = tid & 15;
  const int am = tid >> 2, ak = (tid & 3) << 2;
  const int bk = tid >> 4, bn = (tid & 15) << 2;
  float acc[4][4] = {};
  for (int k0 = 0; k0 < D_IN; k0 += 16) {
    float4 av = make_float4(0.f, 0.f, 0.f, 0.f);
    if (row0 + am < N_NODES)
      av = *(const float4*)(X + (size_t)(row0 + am) * D_IN + k0 + ak);
    float4 bv = *(const float4*)(W + (size_t)(k0 + bk) * D_IN + col0 + bn);
    __syncthreads();
    As[ak + 0][am] = av.x; As[ak + 1][am] = av.y;
    As[ak + 2][am] = av.z; As[ak + 3][am] = av.w;
    *(float4*)&Bs[bk][bn] = bv;
    __syncthreads();
#pragma unroll
    for (int kk = 0; kk < 16; kk++) {  // strictly increasing k
      float4 a = *(const float4*)&As[kk][ty << 2];
      float4 b = *(const float4*)&Bs[kk][tx << 2];
      float aa[4] = {a.x, a.y, a.z, a.w};
      float bb[4] = {b.x, b.y, b.z, b.w};
#pragma unroll
      for (int i = 0; i < 4; i++)
#pragma unroll
        for (int j = 0; j < 4; j++) acc[i][j] = fmaf(aa[i], bb[j], acc[i][j]);
    }
  }
  const int col = col0 + (tx << 2);
  const int kb = col >> 6, c = (col >> 3) & 7;
  const int cofs = kb * 16384 + c * 2048 + ((col & 7) << 1);
#pragma unroll
  for (int i = 0; i < 4; i++) {
    int r = row0 + (ty << 2) + i;
    if (r < N_NODES) {
      *(float4*)(H + (size_t)r * D_IN + col) =
          make_float4(acc[i][0], acc[i][1], acc[i][2], acc[i][3]);
      ushort4 s;
      s.x = f2bf(acc[i][0]); s.y = f2bf(acc[i][1]);
      s.z = f2bf(acc[i][2]); s.w = f2bf(acc[i][3]);
      int t = r >> 7, rl = r & 127;
      char* base = (t < TSPLIT) ? (HbMain + (size_t)t * 131072)
                                : (HbTail + (size_t)(t - TSPLIT) * 131072);
      *(ushort4*)(base + cofs + (((rl + 2 * c) & 127) << 4)) = s;
    }
  }
}

// ---------------------------------------------------------------------------
// P[c][o] = CB[c]·HW[:,o] in fp64 (stored fp32). Logit path only.
// ---------------------------------------------------------------------------
__global__ __launch_bounds__(256) void k_gemm_P(const float* __restrict__ CB,
                                                const float* __restrict__ HW,
                                                float* __restrict__ P) {
  __shared__ float As[16][68];
  __shared__ float Bs[16][68];
  const int tid = threadIdx.x;
  const int c0 = blockIdx.x * 64;
  const int o0 = blockIdx.y * 64;
  const int ty = tid >> 4, tx = tid & 15;
  const int am = tid >> 2, ak = (tid & 3) << 2;
  const int bk = tid >> 4, bn = (tid & 15) << 2;
  double acc[4][4] = {};
  for (int k0 = 0; k0 < D_IN; k0 += 16) {
    float4 av = *(const float4*)(CB + (size_t)(c0 + am) * D_IN + k0 + ak);
    float4 bv = *(const float4*)(HW + (size_t)(k0 + bk) * D_OUT + o0 + bn);
    __syncthreads();
    As[ak + 0][am] = av.x; As[ak + 1][am] = av.y;
    As[ak + 2][am] = av.z; As[ak + 3][am] = av.w;
    *(float4*)&Bs[bk][bn] = bv;
    __syncthreads();
#pragma unroll
    for (int kk = 0; kk < 16; kk++) {
      float4 a = *(const float4*)&As[kk][ty << 2];
      float4 b = *(const float4*)&Bs[kk][tx << 2];
      double aa[4] = {a.x, a.y, a.z, a.w};
      double bb[4] = {b.x, b.y, b.z, b.w};
#pragma unroll
      for (int i = 0; i < 4; i++)
#pragma unroll
        for (int j = 0; j < 4; j++) acc[i][j] = fma(aa[i], bb[j], acc[i][j]);
    }
  }
#pragma unroll
  for (int i = 0; i < 4; i++)
#pragma unroll
    for (int j = 0; j < 4; j++)
      P[(size_t)(c0 + (ty << 2) + i) * D_OUT + o0 + (tx << 2) + j] =
          (float)acc[i][j];
}

// ---------------------------------------------------------------------------
// MFMA candidate pass v4: staging reads PACKED-SWIZZLED global tiles
// (contiguous 1KB per wave-instruction) into LINEAR LDS; the swizzle is
// pre-baked into the global layout by k_h_np / k_cb2bf. Fragment reads,
// sync structure, MFMA k-order, score/scan identical to v3 -> scores
// bit-identical. LDS union unchanged:
// { buf0 A16K|B16K buf1 A16K|B16K (64KB) | ScT[128][128] 64KB }.
// ---------------------------------------------------------------------------
__global__ __launch_bounds__(256, 2) void k_mfma_cand(
    const char* __restrict__ HbMain, const char* __restrict__ HbTail,
    const char* __restrict__ CBb_sw, const float* __restrict__ CBSQ,
    float* __restrict__ candS, int* __restrict__ candI) {
  __shared__ __align__(16) char LDS_RAW[65536];
  float* Sc = (float*)LDS_RAW;
  const int tid  = threadIdx.x;
  const int lane = tid & 63, wave = tid >> 6;
  const int quad = lane >> 4, l16 = lane & 15;
  const int wy = wave >> 1, wx = wave & 1;
  const int row0 = blockIdx.x * 128;
  const int srow = tid >> 1, shalf = tid & 1;

  const int t = blockIdx.x;
  const char* tbaseA = (t < TSPLIT)
                           ? (HbMain + (size_t)t * 131072)
                           : (HbTail + (size_t)(t - TSPLIT) * 131072);
  const char* gA = tbaseA + tid * 16;        // per-lane global src (A)
  const char* gB0 = CBb_sw + tid * 16;       // per-lane global src (B)
  const unsigned lbase = (unsigned)(wave << 10);  // wave-uniform LDS base

  float rs[8]; int ri[8];
#pragma unroll
  for (int k = 0; k < 8; k++) { rs[k] = 3.4e38f; ri[k] = 0x7fffffff; }

  for (int ct = 0; ct < NUM_CODES / 128; ct++) {
    const int code0 = ct * 128;
    const char* gB = gB0 + (size_t)ct * 131072;
    f32x4 acc[4][4];
#pragma unroll
    for (int rf = 0; rf < 4; rf++)
#pragma unroll
      for (int cf = 0; cf < 4; cf++)
        acc[rf][cf] = (f32x4){0.f, 0.f, 0.f, 0.f};

    __syncthreads();  // previous scan done -> slab region reusable
    // prologue: stage kb=0 into buf0 (contiguous 16KB per slab)
#pragma unroll
    for (int it = 0; it < 4; it++) {
      gload16(gA + (it << 12), LDS_RAW + (it << 12) + lbase);
      gload16(gB + (it << 12), LDS_RAW + 16384 + (it << 12) + lbase);
    }
    for (int kb = 0; kb < 8; kb++) {  // BK = 64, double-buffered
      __syncthreads();  // buf[kb&1] staged (vmcnt drain) + prev reads done
      if (kb < 7) {     // issue next stage BEFORE compute
        const unsigned nb = (unsigned)(((kb + 1) & 1) << 15);
        const unsigned ko = (unsigned)((kb + 1) << 14);
#pragma unroll
        for (int it = 0; it < 4; it++) {
          gload16(gA + ko + (it << 12), LDS_RAW + nb + (it << 12) + lbase);
          gload16(gB + ko + (it << 12),
                  LDS_RAW + nb + 16384 + (it << 12) + lbase);
        }
      }
      const char* bufA = LDS_RAW + ((kb & 1) << 15);
      const char* bufB = bufA + 16384;
#pragma unroll
      for (int s = 0; s < 2; s++) {  // 2 MFMA k-steps of 32
        int cidx = s * 4 + quad;
        bf16x8 af[4], bfr[4];
#pragma unroll
        for (int rf = 0; rf < 4; rf++) {
          int arow = wy * 64 + rf * 16 + l16;
          af[rf] = *(const bf16x8*)(bufA + cidx * 2048 +
                                    (((arow + 2 * cidx) & 127) << 4));
        }
#pragma unroll
        for (int cf = 0; cf < 4; cf++) {
          int brow = wx * 64 + cf * 16 + l16;
          bfr[cf] = *(const bf16x8*)(bufB + cidx * 2048 +
                                     (((brow + 2 * cidx) & 127) << 4));
        }
#pragma unroll
        for (int rf = 0; rf < 4; rf++)
#pragma unroll
          for (int cf = 0; cf < 4; cf++)
            acc[rf][cf] = __builtin_amdgcn_mfma_f32_16x16x32_bf16(
                af[rf], bfr[cf], acc[rf][cf], 0, 0, 0);
      }
    }
    __syncthreads();  // K done, slabs dead -> ScT region reusable
    // scores -> ScT[row][128], group-swizzled. C/D: col=lane&15, row=quad*4+r
#pragma unroll
    for (int cf = 0; cf < 4; cf++) {
      int code = wx * 64 + cf * 16 + l16;
      float cq = CBSQ[code0 + code];
      int g = code >> 2;
      int e = code & 3;
#pragma unroll
      for (int rf = 0; rf < 4; rf++) {
        int rowb = wy * 64 + rf * 16 + quad * 4;
#pragma unroll
        for (int r = 0; r < 4; r++) {
          float s = fmaf(-2.0f, acc[rf][cf][r], cq);
          int row = rowb + r;
          int p = (g & 24) | ((g ^ row) & 7);
          Sc[(size_t)row * 128 + (p << 2) + e] = s;
        }
      }
    }
    __syncthreads();
    // scan: thread (srow, shalf): preload 16 f32x4 (visit-swizzled), then
    // min group-reject + insertion (strict <, ascending code order).
    f32x4 vv[16];
    const float* rowbase = Sc + (size_t)srow * 128;
#pragma unroll
    for (int j = 0; j < 16; j++) {
      int g = shalf * 16 + j;
      int p = (g & 24) | ((g ^ srow) & 7);
      vv[j] = *(const f32x4*)(rowbase + (p << 2));
    }
#pragma unroll
    for (int j = 0; j < 16; j++) {
      f32x4 v = vv[j];
      float mn = fminf(fminf(v[0], v[1]), fminf(v[2], v[3]));
      if (mn < rs[7]) {
        int cb = code0 + shalf * 64 + (j << 2);
#pragma unroll
        for (int e = 0; e < 4; e++) {
          if (v[e] < rs[7]) {
            rs[7] = v[e]; ri[7] = cb + e;
#pragma unroll
            for (int t2 = 7; t2 > 0; t2--) {
              if (rs[t2] < rs[t2 - 1]) {
                float tf = rs[t2 - 1]; rs[t2 - 1] = rs[t2]; rs[t2] = tf;
                int tc = ri[t2 - 1]; ri[t2 - 1] = ri[t2]; ri[t2] = tc;
              }
            }
          }
        }
      }
    }
  }
  int grow = row0 + srow;
  if (grow < N_NODES) {
#pragma unroll
    for (int k = 0; k < 8; k++) {
      candS[(size_t)grow * NCAND + shalf * 8 + k] = rs[k];
      candI[(size_t)grow * NCAND + shalf * 8 + k] = ri[k];
    }
  }
}

// ---------------------------------------------------------------------------
// np-exact rescore of candidates within RESCORE_MARGIN of the 4th-best approx
// score; exact fp32 sequential-k chain + np combine; top-4 (ties->lower idx).
// Block: 16 rows x 16 candidates.
// ---------------------------------------------------------------------------
__global__ __launch_bounds__(256) void k_rescore(
    const float* __restrict__ H, const float* __restrict__ CB,
    const float* __restrict__ CBSQ, const float* __restrict__ HSQ,
    const float* __restrict__ candS, const int* __restrict__ candI,
    int* __restrict__ cand4) {
  __shared__ float hs[16][516];
  __shared__ float ss[16][16];
  __shared__ int   ii[16][16];
  __shared__ float sres[16][16];
  const int tid = threadIdx.x;
  const int r0 = blockIdx.x * 16;
#pragma unroll
  for (int it = 0; it < 8; it++) {  // 2048 float4 tasks: coop-load 16 H rows
    int id = tid + it * 256;
    int row = id >> 7, f4 = id & 127;
    float4 v = *(const float4*)(H + (size_t)(r0 + row) * D_IN + f4 * 4);
    *(float4*)&hs[row][f4 * 4] = v;
  }
  {
    int row = tid >> 4, j = tid & 15;
    ss[row][j] = candS[(size_t)(r0 + row) * NCAND + j];
    ii[row][j] = candI[(size_t)(r0 + row) * NCAND + j];
  }
  __syncthreads();
  const int row = tid >> 4, j = tid & 15;
  // 4th-smallest approx score of this row's 16 candidates
  float m[4] = {3.4e38f, 3.4e38f, 3.4e38f, 3.4e38f};
  for (int t = 0; t < 16; t++) {
    float s = ss[row][t];
    if (s < m[3]) {
      m[3] = s;
#pragma unroll
      for (int u = 3; u > 0; u--)
        if (m[u] < m[u - 1]) { float tt = m[u - 1]; m[u - 1] = m[u]; m[u] = tt; }
    }
  }
  const float thr = m[3] + RESCORE_MARGIN;
  const float as = ss[row][j];
  const int ci = ii[row][j];
  float sc = 3.4e38f;
  if (as <= thr) {
    const float4* cbp = (const float4*)(CB + (size_t)ci * D_IN);
    float d = 0.f;
    for (int k = 0; k < 128; k++) {  // strict k order: single FMA chain
      float4 c4 = cbp[k];
      float4 h4 = *(const float4*)&hs[row][k * 4];
      d = fmaf(h4.x, c4.x, d);
      d = fmaf(h4.y, c4.y, d);
      d = fmaf(h4.z, c4.z, d);
      d = fmaf(h4.w, c4.w, d);
    }
    float t1 = __fsub_rn(HSQ[r0 + row], 2.0f * d);  // 2*d exact
    sc = __fadd_rn(t1, CBSQ[ci]);                   // np combine order
  }
  sres[row][j] = sc;
  __syncthreads();
  if (j == 0) {
    float bs[4]; int bi[4];
#pragma unroll
    for (int k = 0; k < 4; k++) { bs[k] = 3.4e38f; bi[k] = 0x7fffffff; }
    for (int t = 0; t < 16; t++) {
      float s = sres[row][t]; int c = ii[row][t];
      if (better(s, c, bs[3], bi[3])) {
        bs[3] = s; bi[3] = c;
#pragma unroll
        for (int u = 3; u > 0; u--) {
          if (better(bs[u], bi[u], bs[u - 1], bi[u - 1])) {
            float tf = bs[u - 1]; bs[u - 1] = bs[u]; bs[u] = tf;
            int tc = bi[u - 1]; bi[u - 1] = bi[u]; bi[u] = tc;
          }
        }
      }
    }
#pragma unroll
    for (int k = 0; k < 4; k++) cand4[(size_t)(r0 + row) * 4 + k] = bi[k];
  }
}

// ---------------------------------------------------------------------------
// OUT[row] = 0.25 * (P[c0]+P[c1]+P[c2]+P[c3]) + bias. One wave per row.
// ---------------------------------------------------------------------------
__global__ __launch_bounds__(256) void k_out(const int* __restrict__ cand4,
                                             const float* __restrict__ P,
                                             const float* __restrict__ HB,
                                             float* __restrict__ OUT) {
  const int lane = threadIdx.x & 63;
  const int row = blockIdx.x * 4 + (threadIdx.x >> 6);
  if (row >= N_NODES) return;
  const int c0 = cand4[(size_t)row * 4 + 0];
  const int c1 = cand4[(size_t)row * 4 + 1];
  const int c2 = cand4[(size_t)row * 4 + 2];
  const int c3 = cand4[(size_t)row * 4 + 3];
  const int col = lane << 2;
  float4 p0 = *(const float4*)(P + (size_t)c0 * D_OUT + col);
  float4 p1 = *(const float4*)(P + (size_t)c1 * D_OUT + col);
  float4 p2 = *(const float4*)(P + (size_t)c2 * D_OUT + col);
  float4 p3 = *(const float4*)(P + (size_t)c3 * D_OUT + col);
  float4 b = *(const float4*)(HB + col);
  float4 o;
  o.x = 0.25f * (((p0.x + p1.x) + p2.x) + p3.x) + b.x;
  o.y = 0.25f * (((p0.y + p1.y) + p2.y) + p3.y) + b.y;
  o.z = 0.25f * (((p0.z + p1.z) + p2.z) + p3.z) + b.z;
  o.w = 0.25f * (((p0.w + p1.w) + p2.w) + p3.w) + b.w;
  *(float4*)(OUT + (size_t)row * D_OUT + col) = o;
}

// ---------------------------------------------------------------------------
extern "C" void kernel_launch(void* const* d_in, const int* in_sizes, int n_in,
                              void* d_out, int out_size, void* d_ws,
                              size_t ws_size, hipStream_t stream) {
  const float* X  = (const float*)d_in[0];
  const float* LP = (const float*)d_in[1];
  const float* CB = (const float*)d_in[2];
  const float* HW = (const float*)d_in[3];
  const float* HB = (const float*)d_in[4];
  float* OUT = (float*)d_out;

  // d_out (102.4 MB) holds packed-swizzled Hb tiles [0,TSPLIT); the last 2
  // tiles (256 KB) live in ws tail. Fully consumed by k_mfma_cand before
  // k_out overwrites.
  char* HbMain = (char*)d_out;

  char* ws = (char*)d_ws;
  size_t off = 0;
  float* H = (float*)(ws + off);      off += (size_t)N_NODES * D_IN * 4;     // 204.8 MB
  float* P = (float*)(ws + off);      off += (size_t)NUM_CODES * D_OUT * 4;  // 2 MB
  char* CBbS = (char*)(ws + off);
  off += (size_t)NUM_CODES * D_IN * 2;                                       // 2 MB
  float* CBSQ = (float*)(ws + off);   off += (size_t)NUM_CODES * 4;
  float* HSQ = (float*)(ws + off);    off += (size_t)N_NODES * 4;
  off = (off + 255) & ~(size_t)255;
  float* candS = (float*)(ws + off);  off += (size_t)N_NODES * NCAND * 4;    // 6.4 MB
  int* candI = (int*)(ws + off);      off += (size_t)N_NODES * NCAND * 4;    // 6.4 MB
  int* cand4 = (int*)(ws + off);      off += (size_t)N_NODES * 4 * 4;        // 1.6 MB
  off = (off + 255) & ~(size_t)255;
  char* HbTail = ws + off;            off += 2 * 131072;                     // 256 KB
  // total ~224.3 MB

  const int row64 = (N_NODES + 63) / 64;
  const int row128 = (N_NODES + 127) / 128;

  k_rowsq<<<(NUM_CODES + 255) / 256, 256, 0, stream>>>(CB, NUM_CODES, CBSQ);
  k_cb2bf<<<NUM_CODES * 64 / 256, 256, 0, stream>>>(CB, CBbS);
  k_gemm_P<<<dim3(NUM_CODES / 64, D_OUT / 64), 256, 0, stream>>>(CB, HW, P);
  k_h_np<<<dim3(row64, D_IN / 64), 256, 0, stream>>>(X, LP, H, HbMain, HbTail);
  k_rowsq<<<(N_NODES + 255) / 256, 256, 0, stream>>>(H, N_NODES, HSQ);
  k_mfma_cand<<<row128, 256, 0, stream>>>(HbMain, HbTail, CBbS, CBSQ, candS,
                                          candI);
  k_rescore<<<N_NODES / 16, 256, 0, stream>>>(H, CB, CBSQ, HSQ, candS, candI,
                                              cand4);
  k_out<<<N_NODES / 4, 256, 0, stream>>>(cand4, P, HB, OUT);
}

// Round 6
// 1996.930 us; speedup vs baseline: 1.3071x; 1.0596x over previous
//
#include <hip/hip_runtime.h>

#define N_NODES   100000
#define D_IN      512
#define NUM_CODES 2048
#define D_OUT     256
#define NCAND     16
#define RESCORE_MARGIN 0.05f
#define TSPLIT    780   // packed-Hb tiles [0,780) in d_out, [780,782) in ws tail

typedef float f32x4  __attribute__((ext_vector_type(4)));
typedef short bf16x8 __attribute__((ext_vector_type(8)));

__device__ __forceinline__ bool better(float s, int i, float S, int I) {
  return (s < S) || (s == S && i < I);
}

__device__ __forceinline__ unsigned short f2bf(float f) {
  unsigned int u = __float_as_uint(f);
  u = (u + 0x7fffu + ((u >> 16) & 1u)) >> 16;  // RNE
  return (unsigned short)u;
}

// async global->LDS, 16B per lane; lds ptr must be the wave-uniform base
// (HW writes lane i at base + i*16).
typedef const __attribute__((address_space(1))) unsigned int* gas_ptr;
typedef __attribute__((address_space(3))) unsigned int* las_ptr;
__device__ __forceinline__ void gload16(const void* g, void* l) {
  __builtin_amdgcn_global_load_lds((gas_ptr)g, (las_ptr)l, 16, 0, 0);
}

// packed-swizzled tile layout (both Hb and CBb):
//   tile t (128 rows), K-block kb (64 elems), chunk c (8 elems), row r:
//   byte = t*131072 + kb*16384 + c*2048 + ((r+2c)&127)*16
// == the LDS slab image; staging becomes contiguous-global -> linear-LDS.

// ---------------------------------------------------------------------------
// numpy pairwise sum-of-squares over a 512-float row (np-exact; see r3).
// ---------------------------------------------------------------------------
__device__ __forceinline__ float np_pairwise_sq512(const float* __restrict__ a) {
  float tot[4];
#pragma unroll
  for (int b = 0; b < 4; b++) {
    const float* p = a + (b << 7);
    float r[8];
    {
      float4 q0 = *(const float4*)(p);
      float4 q1 = *(const float4*)(p + 4);
      r[0] = __fmul_rn(q0.x, q0.x); r[1] = __fmul_rn(q0.y, q0.y);
      r[2] = __fmul_rn(q0.z, q0.z); r[3] = __fmul_rn(q0.w, q0.w);
      r[4] = __fmul_rn(q1.x, q1.x); r[5] = __fmul_rn(q1.y, q1.y);
      r[6] = __fmul_rn(q1.z, q1.z); r[7] = __fmul_rn(q1.w, q1.w);
    }
    for (int i = 8; i < 128; i += 8) {
      float4 u0 = *(const float4*)(p + i);
      float4 u1 = *(const float4*)(p + i + 4);
      r[0] = __fadd_rn(r[0], __fmul_rn(u0.x, u0.x));
      r[1] = __fadd_rn(r[1], __fmul_rn(u0.y, u0.y));
      r[2] = __fadd_rn(r[2], __fmul_rn(u0.z, u0.z));
      r[3] = __fadd_rn(r[3], __fmul_rn(u0.w, u0.w));
      r[4] = __fadd_rn(r[4], __fmul_rn(u1.x, u1.x));
      r[5] = __fadd_rn(r[5], __fmul_rn(u1.y, u1.y));
      r[6] = __fadd_rn(r[6], __fmul_rn(u1.z, u1.z));
      r[7] = __fadd_rn(r[7], __fmul_rn(u1.w, u1.w));
    }
    float t01 = __fadd_rn(r[0], r[1]);
    float t23 = __fadd_rn(r[2], r[3]);
    float t45 = __fadd_rn(r[4], r[5]);
    float t67 = __fadd_rn(r[6], r[7]);
    tot[b] = __fadd_rn(__fadd_rn(t01, t23), __fadd_rn(t45, t67));
  }
  return __fadd_rn(__fadd_rn(tot[0], tot[1]), __fadd_rn(tot[2], tot[3]));
}

__global__ __launch_bounds__(256) void k_rowsq(const float* __restrict__ A,
                                               int nrows,
                                               float* __restrict__ out) {
  int r = blockIdx.x * 256 + threadIdx.x;
  if (r >= nrows) return;
  out[r] = np_pairwise_sq512(A + (size_t)r * D_IN);
}

// ---------------------------------------------------------------------------
// CBb_sw = bf16(CB) in packed-swizzled tile layout. 131072 cells of 16B.
// ---------------------------------------------------------------------------
__global__ __launch_bounds__(256) void k_cb2bf(const float* __restrict__ CB,
                                               char* __restrict__ CBb_sw) {
  int id = blockIdx.x * 256 + threadIdx.x;  // [0, 131072)
  int code = id >> 6, cell = id & 63;
  int kb = cell >> 3, c = cell & 7;
  int ct = code >> 7, rr = code & 127;
  const float* src = CB + (size_t)code * D_IN + (cell << 3);
  float4 v0 = *(const float4*)src;
  float4 v1 = *(const float4*)(src + 4);
  unsigned int w0 = (unsigned)f2bf(v0.x) | ((unsigned)f2bf(v0.y) << 16);
  unsigned int w1 = (unsigned)f2bf(v0.z) | ((unsigned)f2bf(v0.w) << 16);
  unsigned int w2 = (unsigned)f2bf(v1.x) | ((unsigned)f2bf(v1.y) << 16);
  unsigned int w3 = (unsigned)f2bf(v1.z) | ((unsigned)f2bf(v1.w) << 16);
  *(uint4*)(CBb_sw + (size_t)(ct * 8 + kb) * 16384 + c * 2048 +
            (((rr + 2 * c) & 127) << 4)) = make_uint4(w0, w1, w2, w3);
}

// ---------------------------------------------------------------------------
// H = X @ LP (np-exact fp32, single sequential-k FMA chain; verified r3).
// Also emits packed-swizzled bf16(H) for the MFMA candidate pass.
// ---------------------------------------------------------------------------
__global__ __launch_bounds__(256) void k_h_np(const float* __restrict__ X,
                                              const float* __restrict__ W,
                                              float* __restrict__ H,
                                              char* __restrict__ HbMain,
                                              char* __restrict__ HbTail) {
  __shared__ float As[16][68];
  __shared__ float Bs[16][68];
  const int tid = threadIdx.x;
  const int row0 = blockIdx.x * 64;
  const int col0 = blockIdx.y * 64;
  const int ty = tid >> 4, tx = tid & 15;
  const int am = tid >> 2, ak = (tid & 3) << 2;
  const int bk = tid >> 4, bn = (tid & 15) << 2;
  float acc[4][4] = {};
  for (int k0 = 0; k0 < D_IN; k0 += 16) {
    float4 av = make_float4(0.f, 0.f, 0.f, 0.f);
    if (row0 + am < N_NODES)
      av = *(const float4*)(X + (size_t)(row0 + am) * D_IN + k0 + ak);
    float4 bv = *(const float4*)(W + (size_t)(k0 + bk) * D_IN + col0 + bn);
    __syncthreads();
    As[ak + 0][am] = av.x; As[ak + 1][am] = av.y;
    As[ak + 2][am] = av.z; As[ak + 3][am] = av.w;
    *(float4*)&Bs[bk][bn] = bv;
    __syncthreads();
#pragma unroll
    for (int kk = 0; kk < 16; kk++) {  // strictly increasing k
      float4 a = *(const float4*)&As[kk][ty << 2];
      float4 b = *(const float4*)&Bs[kk][tx << 2];
      float aa[4] = {a.x, a.y, a.z, a.w};
      float bb[4] = {b.x, b.y, b.z, b.w};
#pragma unroll
      for (int i = 0; i < 4; i++)
#pragma unroll
        for (int j = 0; j < 4; j++) acc[i][j] = fmaf(aa[i], bb[j], acc[i][j]);
    }
  }
  const int col = col0 + (tx << 2);
  const int kb = col >> 6, c = (col >> 3) & 7;
  const int cofs = kb * 16384 + c * 2048 + ((col & 7) << 1);
#pragma unroll
  for (int i = 0; i < 4; i++) {
    int r = row0 + (ty << 2) + i;
    if (r < N_NODES) {
      *(float4*)(H + (size_t)r * D_IN + col) =
          make_float4(acc[i][0], acc[i][1], acc[i][2], acc[i][3]);
      ushort4 s;
      s.x = f2bf(acc[i][0]); s.y = f2bf(acc[i][1]);
      s.z = f2bf(acc[i][2]); s.w = f2bf(acc[i][3]);
      int t = r >> 7, rl = r & 127;
      char* base = (t < TSPLIT) ? (HbMain + (size_t)t * 131072)
                                : (HbTail + (size_t)(t - TSPLIT) * 131072);
      *(ushort4*)(base + cofs + (((rl + 2 * c) & 127) << 4)) = s;
    }
  }
}

// ---------------------------------------------------------------------------
// P[c][o] = CB[c]·HW[:,o] in fp64 (stored fp32). Logit path only.
// ---------------------------------------------------------------------------
__global__ __launch_bounds__(256) void k_gemm_P(const float* __restrict__ CB,
                                                const float* __restrict__ HW,
                                                float* __restrict__ P) {
  __shared__ float As[16][68];
  __shared__ float Bs[16][68];
  const int tid = threadIdx.x;
  const int c0 = blockIdx.x * 64;
  const int o0 = blockIdx.y * 64;
  const int ty = tid >> 4, tx = tid & 15;
  const int am = tid >> 2, ak = (tid & 3) << 2;
  const int bk = tid >> 4, bn = (tid & 15) << 2;
  double acc[4][4] = {};
  for (int k0 = 0; k0 < D_IN; k0 += 16) {
    float4 av = *(const float4*)(CB + (size_t)(c0 + am) * D_IN + k0 + ak);
    float4 bv = *(const float4*)(HW + (size_t)(k0 + bk) * D_OUT + o0 + bn);
    __syncthreads();
    As[ak + 0][am] = av.x; As[ak + 1][am] = av.y;
    As[ak + 2][am] = av.z; As[ak + 3][am] = av.w;
    *(float4*)&Bs[bk][bn] = bv;
    __syncthreads();
#pragma unroll
    for (int kk = 0; kk < 16; kk++) {
      float4 a = *(const float4*)&As[kk][ty << 2];
      float4 b = *(const float4*)&Bs[kk][tx << 2];
      double aa[4] = {a.x, a.y, a.z, a.w};
      double bb[4] = {b.x, b.y, b.z, b.w};
#pragma unroll
      for (int i = 0; i < 4; i++)
#pragma unroll
        for (int j = 0; j < 4; j++) acc[i][j] = fma(aa[i], bb[j], acc[i][j]);
    }
  }
#pragma unroll
  for (int i = 0; i < 4; i++)
#pragma unroll
    for (int j = 0; j < 4; j++)
      P[(size_t)(c0 + (ty << 2) + i) * D_OUT + o0 + (tx << 2) + j] =
          (float)acc[i][j];
}

// ---------------------------------------------------------------------------
// MFMA candidate pass v5: same data layout as v4 (packed-swizzled global,
// linear-LDS DMA staging, dbuf BK=64). NEW sync discipline (T3/T4): raw
// s_barriers + counted vmcnt(8) so the next tile's 8 DMA loads stay in
// flight ACROSS the barrier instead of being drained by __syncthreads'
// vmcnt(0) every kb-step. Accounting: ct-top __syncthreads fully drains;
// kb-loop body contains no other VMEM ops; so vmcnt(8) == "my 8 current-
// tile loads have landed". MFMA order identical -> scores bit-identical.
// LDS union unchanged: { dbuf 64KB | ScT[128][128] 64KB }.
// ---------------------------------------------------------------------------
__global__ __launch_bounds__(256, 2) void k_mfma_cand(
    const char* __restrict__ HbMain, const char* __restrict__ HbTail,
    const char* __restrict__ CBb_sw, const float* __restrict__ CBSQ,
    float* __restrict__ candS, int* __restrict__ candI) {
  __shared__ __align__(16) char LDS_RAW[65536];
  float* Sc = (float*)LDS_RAW;
  const int tid  = threadIdx.x;
  const int lane = tid & 63, wave = tid >> 6;
  const int quad = lane >> 4, l16 = lane & 15;
  const int wy = wave >> 1, wx = wave & 1;
  const int row0 = blockIdx.x * 128;
  const int srow = tid >> 1, shalf = tid & 1;

  const int t = blockIdx.x;
  const char* tbaseA = (t < TSPLIT)
                           ? (HbMain + (size_t)t * 131072)
                           : (HbTail + (size_t)(t - TSPLIT) * 131072);
  const char* gA = tbaseA + tid * 16;        // per-lane global src (A)
  const char* gB0 = CBb_sw + tid * 16;       // per-lane global src (B)
  const unsigned lbase = (unsigned)(wave << 10);  // wave-uniform LDS base

  float rs[8]; int ri[8];
#pragma unroll
  for (int k = 0; k < 8; k++) { rs[k] = 3.4e38f; ri[k] = 0x7fffffff; }

  for (int ct = 0; ct < NUM_CODES / 128; ct++) {
    const int code0 = ct * 128;
    const char* gB = gB0 + (size_t)ct * 131072;
    f32x4 acc[4][4];
#pragma unroll
    for (int rf = 0; rf < 4; rf++)
#pragma unroll
      for (int cf = 0; cf < 4; cf++)
        acc[rf][cf] = (f32x4){0.f, 0.f, 0.f, 0.f};

    __syncthreads();  // ct top: scan done -> slabs reusable; FULL vmcnt drain
    // prologue: stage kb=0 into buf0 (contiguous 16KB per slab)
#pragma unroll
    for (int it = 0; it < 4; it++) {
      gload16(gA + (it << 12), LDS_RAW + (it << 12) + lbase);
      gload16(gB + (it << 12), LDS_RAW + 16384 + (it << 12) + lbase);
    }
    for (int kb = 0; kb < 8; kb++) {  // BK = 64, dbuf, counted-vmcnt pipeline
      if (kb > 0)
        __builtin_amdgcn_s_barrier();  // A: all waves done reading buf[(kb+1)&1]
      if (kb < 7) {                    // issue next tile, then wait CURRENT only
        const unsigned nb = (unsigned)(((kb + 1) & 1) << 15);
        const unsigned ko = (unsigned)((kb + 1) << 14);
#pragma unroll
        for (int it = 0; it < 4; it++) {
          gload16(gA + ko + (it << 12), LDS_RAW + nb + (it << 12) + lbase);
          gload16(gB + ko + (it << 12),
                  LDS_RAW + nb + 16384 + (it << 12) + lbase);
        }
        asm volatile("s_waitcnt vmcnt(8)" ::: "memory");  // kb's 8 landed;
                                                          // kb+1's 8 in flight
      } else {
        asm volatile("s_waitcnt vmcnt(0)" ::: "memory");  // last tile
      }
      __builtin_amdgcn_sched_barrier(0);
      __builtin_amdgcn_s_barrier();    // B: buf[kb&1] staged for ALL waves
      const char* bufA = LDS_RAW + ((kb & 1) << 15);
      const char* bufB = bufA + 16384;
#pragma unroll
      for (int s = 0; s < 2; s++) {  // 2 MFMA k-steps of 32
        int cidx = s * 4 + quad;
        bf16x8 af[4], bfr[4];
#pragma unroll
        for (int rf = 0; rf < 4; rf++) {
          int arow = wy * 64 + rf * 16 + l16;
          af[rf] = *(const bf16x8*)(bufA + cidx * 2048 +
                                    (((arow + 2 * cidx) & 127) << 4));
        }
#pragma unroll
        for (int cf = 0; cf < 4; cf++) {
          int brow = wx * 64 + cf * 16 + l16;
          bfr[cf] = *(const bf16x8*)(bufB + cidx * 2048 +
                                     (((brow + 2 * cidx) & 127) << 4));
        }
#pragma unroll
        for (int rf = 0; rf < 4; rf++)
#pragma unroll
          for (int cf = 0; cf < 4; cf++)
            acc[rf][cf] = __builtin_amdgcn_mfma_f32_16x16x32_bf16(
                af[rf], bfr[cf], acc[rf][cf], 0, 0, 0);
      }
    }
    __syncthreads();  // K done, slabs dead -> ScT region reusable
    // scores -> ScT[row][128], group-swizzled. C/D: col=lane&15, row=quad*4+r
#pragma unroll
    for (int cf = 0; cf < 4; cf++) {
      int code = wx * 64 + cf * 16 + l16;
      float cq = CBSQ[code0 + code];
      int g = code >> 2;
      int e = code & 3;
#pragma unroll
      for (int rf = 0; rf < 4; rf++) {
        int rowb = wy * 64 + rf * 16 + quad * 4;
#pragma unroll
        for (int r = 0; r < 4; r++) {
          float s = fmaf(-2.0f, acc[rf][cf][r], cq);
          int row = rowb + r;
          int p = (g & 24) | ((g ^ row) & 7);
          Sc[(size_t)row * 128 + (p << 2) + e] = s;
        }
      }
    }
    __syncthreads();
    // scan: thread (srow, shalf): preload 16 f32x4 (visit-swizzled), then
    // min group-reject + insertion (strict <, ascending code order).
    f32x4 vv[16];
    const float* rowbase = Sc + (size_t)srow * 128;
#pragma unroll
    for (int j = 0; j < 16; j++) {
      int g = shalf * 16 + j;
      int p = (g & 24) | ((g ^ srow) & 7);
      vv[j] = *(const f32x4*)(rowbase + (p << 2));
    }
#pragma unroll
    for (int j = 0; j < 16; j++) {
      f32x4 v = vv[j];
      float mn = fminf(fminf(v[0], v[1]), fminf(v[2], v[3]));
      if (mn < rs[7]) {
        int cb = code0 + shalf * 64 + (j << 2);
#pragma unroll
        for (int e = 0; e < 4; e++) {
          if (v[e] < rs[7]) {
            rs[7] = v[e]; ri[7] = cb + e;
#pragma unroll
            for (int t2 = 7; t2 > 0; t2--) {
              if (rs[t2] < rs[t2 - 1]) {
                float tf = rs[t2 - 1]; rs[t2 - 1] = rs[t2]; rs[t2] = tf;
                int tc = ri[t2 - 1]; ri[t2 - 1] = ri[t2]; ri[t2] = tc;
              }
            }
          }
        }
      }
    }
  }
  int grow = row0 + srow;
  if (grow < N_NODES) {
#pragma unroll
    for (int k = 0; k < 8; k++) {
      candS[(size_t)grow * NCAND + shalf * 8 + k] = rs[k];
      candI[(size_t)grow * NCAND + shalf * 8 + k] = ri[k];
    }
  }
}

// ---------------------------------------------------------------------------
// np-exact rescore of candidates within RESCORE_MARGIN of the 4th-best approx
// score; exact fp32 sequential-k chain + np combine; top-4 (ties->lower idx).
// Block: 16 rows x 16 candidates.
// ---------------------------------------------------------------------------
__global__ __launch_bounds__(256) void k_rescore(
    const float* __restrict__ H, const float* __restrict__ CB,
    const float* __restrict__ CBSQ, const float* __restrict__ HSQ,
    const float* __restrict__ candS, const int* __restrict__ candI,
    int* __restrict__ cand4) {
  __shared__ float hs[16][516];
  __shared__ float ss[16][16];
  __shared__ int   ii[16][16];
  __shared__ float sres[16][16];
  const int tid = threadIdx.x;
  const int r0 = blockIdx.x * 16;
#pragma unroll
  for (int it = 0; it < 8; it++) {  // 2048 float4 tasks: coop-load 16 H rows
    int id = tid + it * 256;
    int row = id >> 7, f4 = id & 127;
    float4 v = *(const float4*)(H + (size_t)(r0 + row) * D_IN + f4 * 4);
    *(float4*)&hs[row][f4 * 4] = v;
  }
  {
    int row = tid >> 4, j = tid & 15;
    ss[row][j] = candS[(size_t)(r0 + row) * NCAND + j];
    ii[row][j] = candI[(size_t)(r0 + row) * NCAND + j];
  }
  __syncthreads();
  const int row = tid >> 4, j = tid & 15;
  // 4th-smallest approx score of this row's 16 candidates
  float m[4] = {3.4e38f, 3.4e38f, 3.4e38f, 3.4e38f};
  for (int t = 0; t < 16; t++) {
    float s = ss[row][t];
    if (s < m[3]) {
      m[3] = s;
#pragma unroll
      for (int u = 3; u > 0; u--)
        if (m[u] < m[u - 1]) { float tt = m[u - 1]; m[u - 1] = m[u]; m[u] = tt; }
    }
  }
  const float thr = m[3] + RESCORE_MARGIN;
  const float as = ss[row][j];
  const int ci = ii[row][j];
  float sc = 3.4e38f;
  if (as <= thr) {
    const float4* cbp = (const float4*)(CB + (size_t)ci * D_IN);
    float d = 0.f;
    for (int k = 0; k < 128; k++) {  // strict k order: single FMA chain
      float4 c4 = cbp[k];
      float4 h4 = *(const float4*)&hs[row][k * 4];
      d = fmaf(h4.x, c4.x, d);
      d = fmaf(h4.y, c4.y, d);
      d = fmaf(h4.z, c4.z, d);
      d = fmaf(h4.w, c4.w, d);
    }
    float t1 = __fsub_rn(HSQ[r0 + row], 2.0f * d);  // 2*d exact
    sc = __fadd_rn(t1, CBSQ[ci]);                   // np combine order
  }
  sres[row][j] = sc;
  __syncthreads();
  if (j == 0) {
    float bs[4]; int bi[4];
#pragma unroll
    for (int k = 0; k < 4; k++) { bs[k] = 3.4e38f; bi[k] = 0x7fffffff; }
    for (int t = 0; t < 16; t++) {
      float s = sres[row][t]; int c = ii[row][t];
      if (better(s, c, bs[3], bi[3])) {
        bs[3] = s; bi[3] = c;
#pragma unroll
        for (int u = 3; u > 0; u--) {
          if (better(bs[u], bi[u], bs[u - 1], bi[u - 1])) {
            float tf = bs[u - 1]; bs[u - 1] = bs[u]; bs[u] = tf;
            int tc = bi[u - 1]; bi[u - 1] = bi[u]; bi[u] = tc;
          }
        }
      }
    }
#pragma unroll
    for (int k = 0; k < 4; k++) cand4[(size_t)(r0 + row) * 4 + k] = bi[k];
  }
}

// ---------------------------------------------------------------------------
// OUT[row] = 0.25 * (P[c0]+P[c1]+P[c2]+P[c3]) + bias. One wave per row.
// ---------------------------------------------------------------------------
__global__ __launch_bounds__(256) void k_out(const int* __restrict__ cand4,
                                             const float* __restrict__ P,
                                             const float* __restrict__ HB,
                                             float* __restrict__ OUT) {
  const int lane = threadIdx.x & 63;
  const int row = blockIdx.x * 4 + (threadIdx.x >> 6);
  if (row >= N_NODES) return;
  const int c0 = cand4[(size_t)row * 4 + 0];
  const int c1 = cand4[(size_t)row * 4 + 1];
  const int c2 = cand4[(size_t)row * 4 + 2];
  const int c3 = cand4[(size_t)row * 4 + 3];
  const int col = lane << 2;
  float4 p0 = *(const float4*)(P + (size_t)c0 * D_OUT + col);
  float4 p1 = *(const float4*)(P + (size_t)c1 * D_OUT + col);
  float4 p2 = *(const float4*)(P + (size_t)c2 * D_OUT + col);
  float4 p3 = *(const float4*)(P + (size_t)c3 * D_OUT + col);
  float4 b = *(const float4*)(HB + col);
  float4 o;
  o.x = 0.25f * (((p0.x + p1.x) + p2.x) + p3.x) + b.x;
  o.y = 0.25f * (((p0.y + p1.y) + p2.y) + p3.y) + b.y;
  o.z = 0.25f * (((p0.z + p1.z) + p2.z) + p3.z) + b.z;
  o.w = 0.25f * (((p0.w + p1.w) + p2.w) + p3.w) + b.w;
  *(float4*)(OUT + (size_t)row * D_OUT + col) = o;
}

// ---------------------------------------------------------------------------
extern "C" void kernel_launch(void* const* d_in, const int* in_sizes, int n_in,
                              void* d_out, int out_size, void* d_ws,
                              size_t ws_size, hipStream_t stream) {
  const float* X  = (const float*)d_in[0];
  const float* LP = (const float*)d_in[1];
  const float* CB = (const float*)d_in[2];
  const float* HW = (const float*)d_in[3];
  const float* HB = (const float*)d_in[4];
  float* OUT = (float*)d_out;

  // d_out (102.4 MB) holds packed-swizzled Hb tiles [0,TSPLIT); the last 2
  // tiles (256 KB) live in ws tail. Fully consumed by k_mfma_cand before
  // k_out overwrites.
  char* HbMain = (char*)d_out;

  char* ws = (char*)d_ws;
  size_t off = 0;
  float* H = (float*)(ws + off);      off += (size_t)N_NODES * D_IN * 4;     // 204.8 MB
  float* P = (float*)(ws + off);      off += (size_t)NUM_CODES * D_OUT * 4;  // 2 MB
  char* CBbS = (char*)(ws + off);
  off += (size_t)NUM_CODES * D_IN * 2;                                       // 2 MB
  float* CBSQ = (float*)(ws + off);   off += (size_t)NUM_CODES * 4;
  float* HSQ = (float*)(ws + off);    off += (size_t)N_NODES * 4;
  off = (off + 255) & ~(size_t)255;
  float* candS = (float*)(ws + off);  off += (size_t)N_NODES * NCAND * 4;    // 6.4 MB
  int* candI = (int*)(ws + off);      off += (size_t)N_NODES * NCAND * 4;    // 6.4 MB
  int* cand4 = (int*)(ws + off);      off += (size_t)N_NODES * 4 * 4;        // 1.6 MB
  off = (off + 255) & ~(size_t)255;
  char* HbTail = ws + off;            off += 2 * 131072;                     // 256 KB
  // total ~224.3 MB

  const int row64 = (N_NODES + 63) / 64;
  const int row128 = (N_NODES + 127) / 128;

  k_rowsq<<<(NUM_CODES + 255) / 256, 256, 0, stream>>>(CB, NUM_CODES, CBSQ);
  k_cb2bf<<<NUM_CODES * 64 / 256, 256, 0, stream>>>(CB, CBbS);
  k_gemm_P<<<dim3(NUM_CODES / 64, D_OUT / 64), 256, 0, stream>>>(CB, HW, P);
  k_h_np<<<dim3(row64, D_IN / 64), 256, 0, stream>>>(X, LP, H, HbMain, HbTail);
  k_rowsq<<<(N_NODES + 255) / 256, 256, 0, stream>>>(H, N_NODES, HSQ);
  k_mfma_cand<<<row128, 256, 0, stream>>>(HbMain, HbTail, CBbS, CBSQ, candS,
                                          candI);
  k_rescore<<<N_NODES / 16, 256, 0, stream>>>(H, CB, CBSQ, HSQ, candS, candI,
                                              cand4);
  k_out<<<N_NODES / 4, 256, 0, stream>>>(cand4, P, HB, OUT);
}